// Round 1
// baseline (5928.032 us; speedup 1.0000x reference)
//
#include <hip/hip_runtime.h>
#include <cstdint>

// WeatherSTGNN persistent kernel, round 6: register-resident chain.
// One wave = one batch, zero barriers in the 96-step loop (as before), but the
// inter-stage C -> next A/B fragment transform is now done IN REGISTERS:
// since contraction-dim == C-rows at every hand-off, C (col=lane&31,
// row=(r&3)+8*(r>>2)+4*(lane>>5)) maps to frag (lane=idx+32*((k>>3)&1),
// elem=k&7) by a half-wave exchange = v_cvt_pk_bf16_f32 pairs + 2x
// v_permlane32_swap_b32 per 16-k chunk (cpack8). This deletes the per-wave
// 4KB LDS chain buffer and all 7 per-step LDS write->read round-trips.
// Biases are folded into accumulator INIT (not epilogue adds). Encoder xB is
// read one step ahead (cross-step prefetch); decoder xB is built in registers
// (permlane moves p4,p5 across the hf boundary; statics live in 3 regs).

#define NT 512
#define TSTEPS 48
#define FUT 48

typedef __bf16 bf16;
typedef __attribute__((ext_vector_type(2))) __bf16 bf16x2;
typedef __attribute__((ext_vector_type(8))) __bf16 bf16x8;
typedef __attribute__((ext_vector_type(16))) float f32x16;
typedef unsigned int uint32x4v __attribute__((ext_vector_type(4)));

__device__ __forceinline__ float sigm(float x) { return 1.0f / (1.0f + __expf(-x)); }
__device__ __forceinline__ float tanh_fast(float x) { return 1.0f - 2.0f / (__expf(2.0f * x) + 1.0f); }

__device__ __forceinline__ uint32_t pk2(float x, float y) {
  union { bf16x2 h; uint32_t u; } t;
  t.h[0] = (bf16)x; t.h[1] = (bf16)y;
  return t.u;
}

// C-regs v0..v7 (quads q, q+1 of one 32x32 C tile) -> one bf16x8 A/B-frag
// chunk. Golden map (verified vs cwi): frag lanes<32 <- quad q of src, lanes
// >=32 <- quad q+1; elems 0-3 from hf=0 source half, 4-7 from hf=1.
// permlane32_swap(a,b): r[0]={a.lo,b.lo}, r[1]={a.hi,b.hi}.
__device__ __forceinline__ bf16x8 cpack8(float v0, float v1, float v2, float v3,
                                         float v4, float v5, float v6, float v7) {
  uint32_t a0 = pk2(v0, v1), a1 = pk2(v2, v3);
  uint32_t b0 = pk2(v4, v5), b1 = pk2(v6, v7);
  auto r0 = __builtin_amdgcn_permlane32_swap(a0, b0, false, false);
  auto r1 = __builtin_amdgcn_permlane32_swap(a1, b1, false, false);
  union { uint32x4v u; bf16x8 h; } o;
  o.u = uint32x4v{(uint32_t)r0[0], (uint32_t)r1[0], (uint32_t)r0[1], (uint32_t)r1[1]};
  return o.h;
}

__global__ __launch_bounds__(NT, 2)
void stgnn_kernel(const float* __restrict__ xh, const float* __restrict__ adj,
                  const float* __restrict__ Wenc, const float* __restrict__ benc,
                  const float* __restrict__ Wg1, const float* __restrict__ bg1,
                  const float* __restrict__ Wg2, const float* __restrict__ bg2,
                  const float* __restrict__ Wih, const float* __restrict__ Whh,
                  const float* __restrict__ bih, const float* __restrict__ bhh,
                  const float* __restrict__ Wd1, const float* __restrict__ bd1,
                  const float* __restrict__ Wd2, const float* __restrict__ bd2,
                  float* __restrict__ out) {
  __shared__ __align__(16) bf16 wcatTA[32768];  // Wcat^T A-frag (8 mt x 8 c)
  __shared__ __align__(16) bf16 wg1B[4096];     // Wg1 B-frag (2 nt x 4 c)
  __shared__ __align__(16) bf16 wg2B[4096];     // Wg2 B-frag
  __shared__ __align__(16) bf16 wencTA[1024];   // Wenc^T A-frag (2 mt x 1 c)
  __shared__ __align__(16) bf16 wd1TA[2048];    // Wd1^T A-frag (1 mt x 4 c)
  __shared__ __align__(16) bf16 wd2TA[1024];    // Wd2^T A-frag (1 mt x 2 c, d padded)
  __shared__ __align__(16) float sBenc[64];
  __shared__ __align__(16) float sBg1[64];
  __shared__ __align__(16) float sBg2[64];
  __shared__ __align__(16) float sBih[256];
  __shared__ __align__(16) float sBd1[32];
  __shared__ __align__(16) float sBd2[8];
  __shared__ float sDeg[32];
  __shared__ __align__(16) float sAh[1024];     // normalized Ahat (setup only)
  __shared__ __align__(16) bf16 sXbA[8 * 512];  // per-wave x staging, [node][f pad16]

  const int tid = threadIdx.x;
  const int L   = tid & 63;
  const int w   = tid >> 6;
  const int n5  = L & 31;
  const int hf  = L >> 5;
  const long long b = (long long)blockIdx.x * 8 + w;

  bf16* sXb = sXbA + (w << 9);

  // ---------------- static staging ----------------
  for (int i = tid; i < 1024; i += NT) {
    int f = i >> 6, h = i & 63;
    float v = (f < 11) ? Wenc[f * 64 + h] : 0.0f;
    wencTA[(h >> 5) * 512 + ((h & 31) + 32 * ((f >> 3) & 1)) * 8 + (f & 7)] = (bf16)v;
  }
  for (int i = tid; i < 4096; i += NT) {
    int k = i >> 6, n = i & 63;
    int off = (((n >> 5) * 4 + (k >> 4)) * 64 + (n & 31) + 32 * ((k >> 3) & 1)) * 8 + (k & 7);
    wg1B[off] = (bf16)Wg1[i];
    wg2B[off] = (bf16)Wg2[i];
  }
  for (int i = tid; i < 32768; i += NT) {
    int gc = i >> 7, k = i & 127;
    float v = (k < 64) ? Wih[gc * 64 + k] : Whh[gc * 64 + (k - 64)];
    wcatTA[((gc >> 5) * 8 + (k >> 4)) * 512 + ((gc & 31) + 32 * ((k >> 3) & 1)) * 8 + (k & 7)] = (bf16)v;
  }
  for (int i = tid; i < 2048; i += NT) {
    int k = i >> 5, n = i & 31;
    wd1TA[(k >> 4) * 512 + (n + 32 * ((k >> 3) & 1)) * 8 + (k & 7)] = (bf16)Wd1[k * 32 + n];
  }
  for (int i = tid; i < 1024; i += NT) {
    int k = i >> 5, d = i & 31;
    float v = (d < 6) ? Wd2[k * 6 + d] : 0.0f;
    wd2TA[(k >> 4) * 512 + (d + 32 * ((k >> 3) & 1)) * 8 + (k & 7)] = (bf16)v;
  }
  for (int i = tid; i < 64; i += NT) { sBenc[i] = benc[i]; sBg1[i] = bg1[i]; sBg2[i] = bg2[i]; }
  for (int i = tid; i < 256; i += NT) sBih[i] = bih[i] + bhh[i];
  for (int i = tid; i < 32; i += NT) sBd1[i] = bd1[i];
  if (tid < 8) sBd2[tid] = (tid < 6) ? bd2[tid] : 0.0f;
  if (tid < 32) {
    float s = 0.0f;
    for (int j = 0; j < 32; ++j) s += (j == tid) ? 1.0f : adj[tid * 32 + j];
    sDeg[tid] = 1.0f / sqrtf(fmaxf(s, 1.0f));
  }
  __syncthreads();
  for (int i = tid; i < 1024; i += NT) {
    int ii = i >> 5, jj = i & 31;
    float v = (ii == jj) ? 1.0f : adj[i];
    sAh[i] = sDeg[ii] * v * sDeg[jj];
  }
  __syncthreads();  // last barrier: everything is per-wave / read-only after this
  bf16x8 ahHi[2], ahLo[2];
  #pragma unroll
  for (int c = 0; c < 2; ++c)
    #pragma unroll
    for (int j = 0; j < 8; ++j) {
      int k = 16 * c + 8 * hf + j;
      float v = sAh[n5 * 32 + k];
      bf16 hi = (bf16)v;
      ahHi[c][j] = hi;
      ahLo[c][j] = (bf16)(v - (float)hi);
    }
  // persistent Wenc^T A-frags (on the per-step critical path head)
  bf16x8 wencR[2];
  wencR[0] = *reinterpret_cast<const bf16x8*>(&wencTA[L * 8]);
  wencR[1] = *reinterpret_cast<const bf16x8*>(&wencTA[512 + L * 8]);

  // persistent per-wave registers
  float cx[32];
  #pragma unroll
  for (int i = 0; i < 32; ++i) cx[i] = 0.0f;
  bf16x8 xfhB[8];
  #pragma unroll
  for (int t = 0; t < 8; ++t)
    #pragma unroll
    for (int j = 0; j < 8; ++j) xfhB[t][j] = (bf16)0.0f;
  float predr[4] = {0.f, 0.f, 0.f, 0.f};
  float st0 = 0.f, st1 = 0.f, st2 = 0.f;

  // zero-pad f>=11 forever, then commit step-0 input and prefetch step-1
  for (int i = L; i < 512; i += 64) sXb[i] = (bf16)0.0f;
  float xpre[6];
  #pragma unroll
  for (int t = 0; t < 6; ++t) {
    int i = L + (t << 6);
    xpre[t] = (i < 352) ? xh[b * (TSTEPS * 352) + i] : 0.0f;
  }
  #pragma unroll
  for (int t = 0; t < 6; ++t) {
    int i = L + (t << 6);
    if (i < 352) { int j = i / 11, f = i - j * 11; sXb[(j << 4) + f] = (bf16)xpre[t]; }
  }
  #pragma unroll
  for (int t = 0; t < 6; ++t) {
    int i = L + (t << 6);
    if (i < 352) xpre[t] = xh[b * (TSTEPS * 352) + 352 + i];
  }
  bf16x8 xBcur = *reinterpret_cast<const bf16x8*>(&sXb[(n5 << 4) + (hf << 3)]);

  for (int step = 0; step < TSTEPS + FUT; ++step) {
    const bool de = (step >= TSTEPS);
    const bf16x8 xB = xBcur;  // staged/built one step ago -> no latency here
    if (!de) {
      // commit next step's x, prefetch the one after, pre-read next xB
      if (step + 1 < TSTEPS) {
        #pragma unroll
        for (int t = 0; t < 6; ++t) {
          int i = L + (t << 6);
          if (i < 352) { int j = i / 11, f = i - j * 11; sXb[(j << 4) + f] = (bf16)xpre[t]; }
        }
      }
      if (step + 2 < TSTEPS) {
        #pragma unroll
        for (int t = 0; t < 6; ++t) {
          int i = L + (t << 6);
          if (i < 352) xpre[t] = xh[b * (TSTEPS * 352) + (step + 2) * 352 + i];
        }
      }
      xBcur = *reinterpret_cast<const bf16x8*>(&sXb[(n5 << 4) + (hf << 3)]);
    }
    // ---- enc^T = relu(Wenc^T @ x^T + benc): bias pre-loaded into acc ----
    bf16x8 rA[4];
    #pragma unroll
    for (int mt = 0; mt < 2; ++mt) {
      f32x16 c;
      #pragma unroll
      for (int g = 0; g < 4; ++g) {
        float4 bb = *reinterpret_cast<const float4*>(&sBenc[32 * mt + 8 * g + 4 * hf]);
        c[4*g+0] = bb.x; c[4*g+1] = bb.y; c[4*g+2] = bb.z; c[4*g+3] = bb.w;
      }
      c = __builtin_amdgcn_mfma_f32_32x32x16_bf16(wencR[mt], xB, c, 0, 0, 0);
      float v[16];
      #pragma unroll
      for (int i = 0; i < 16; ++i) v[i] = fmaxf(c[i], 0.0f);
      rA[2*mt]   = cpack8(v[0], v[1], v[2], v[3], v[4], v[5], v[6], v[7]);
      rA[2*mt+1] = cpack8(v[8], v[9], v[10], v[11], v[12], v[13], v[14], v[15]);
    }
    // ---- t1 = enc @ Wg1 ----
    bf16x8 nA[4];
    #pragma unroll
    for (int nt = 0; nt < 2; ++nt) {
      f32x16 c;
      #pragma unroll
      for (int i = 0; i < 16; ++i) c[i] = 0.0f;
      #pragma unroll
      for (int cc = 0; cc < 4; ++cc)
        c = __builtin_amdgcn_mfma_f32_32x32x16_bf16(rA[cc],
              *reinterpret_cast<const bf16x8*>(&wg1B[(nt * 4 + cc) * 512 + L * 8]), c, 0, 0, 0);
      nA[2*nt]   = cpack8(c[0], c[1], c[2], c[3], c[4], c[5], c[6], c[7]);
      nA[2*nt+1] = cpack8(c[8], c[9], c[10], c[11], c[12], c[13], c[14], c[15]);
    }
    // ---- s1^T = relu(t1^T @ Ahat^T + bg1) ----
    #pragma unroll
    for (int mt = 0; mt < 2; ++mt) {
      f32x16 c;
      #pragma unroll
      for (int g = 0; g < 4; ++g) {
        float4 bb = *reinterpret_cast<const float4*>(&sBg1[32 * mt + 8 * g + 4 * hf]);
        c[4*g+0] = bb.x; c[4*g+1] = bb.y; c[4*g+2] = bb.z; c[4*g+3] = bb.w;
      }
      #pragma unroll
      for (int cc = 0; cc < 2; ++cc) {
        c = __builtin_amdgcn_mfma_f32_32x32x16_bf16(nA[mt * 2 + cc], ahHi[cc], c, 0, 0, 0);
        c = __builtin_amdgcn_mfma_f32_32x32x16_bf16(nA[mt * 2 + cc], ahLo[cc], c, 0, 0, 0);
      }
      float v[16];
      #pragma unroll
      for (int i = 0; i < 16; ++i) v[i] = fmaxf(c[i], 0.0f);
      rA[2*mt]   = cpack8(v[0], v[1], v[2], v[3], v[4], v[5], v[6], v[7]);
      rA[2*mt+1] = cpack8(v[8], v[9], v[10], v[11], v[12], v[13], v[14], v[15]);
    }
    // ---- t2 = s1 @ Wg2 ----
    #pragma unroll
    for (int nt = 0; nt < 2; ++nt) {
      f32x16 c;
      #pragma unroll
      for (int i = 0; i < 16; ++i) c[i] = 0.0f;
      #pragma unroll
      for (int cc = 0; cc < 4; ++cc)
        c = __builtin_amdgcn_mfma_f32_32x32x16_bf16(rA[cc],
              *reinterpret_cast<const bf16x8*>(&wg2B[(nt * 4 + cc) * 512 + L * 8]), c, 0, 0, 0);
      nA[2*nt]   = cpack8(c[0], c[1], c[2], c[3], c[4], c[5], c[6], c[7]);
      nA[2*nt+1] = cpack8(c[8], c[9], c[10], c[11], c[12], c[13], c[14], c[15]);
    }
    // ---- xf^T = relu(t2^T @ Ahat^T + bg2) -> xfhB[0..3] ----
    #pragma unroll
    for (int mt = 0; mt < 2; ++mt) {
      f32x16 c;
      #pragma unroll
      for (int g = 0; g < 4; ++g) {
        float4 bb = *reinterpret_cast<const float4*>(&sBg2[32 * mt + 8 * g + 4 * hf]);
        c[4*g+0] = bb.x; c[4*g+1] = bb.y; c[4*g+2] = bb.z; c[4*g+3] = bb.w;
      }
      #pragma unroll
      for (int cc = 0; cc < 2; ++cc) {
        c = __builtin_amdgcn_mfma_f32_32x32x16_bf16(nA[mt * 2 + cc], ahHi[cc], c, 0, 0, 0);
        c = __builtin_amdgcn_mfma_f32_32x32x16_bf16(nA[mt * 2 + cc], ahLo[cc], c, 0, 0, 0);
      }
      float v[16];
      #pragma unroll
      for (int i = 0; i < 16; ++i) v[i] = fmaxf(c[i], 0.0f);
      xfhB[2*mt]   = cpack8(v[0], v[1], v[2], v[3], v[4], v[5], v[6], v[7]);
      xfhB[2*mt+1] = cpack8(v[8], v[9], v[10], v[11], v[12], v[13], v[14], v[15]);
    }
    // ---- LSTM: gates via Wcat^T @ [xf|h]^T; old h kept live until both passes done ----
    bf16x8 hN[4];
    #pragma unroll
    for (int p = 0; p < 2; ++p) {
      f32x16 ga[4];
      #pragma unroll
      for (int a = 0; a < 4; ++a)
        #pragma unroll
        for (int g = 0; g < 4; ++g) {
          float4 bb = *reinterpret_cast<const float4*>(&sBih[a * 64 + 32 * p + 8 * g + 4 * hf]);
          ga[a][4*g+0] = bb.x; ga[a][4*g+1] = bb.y; ga[a][4*g+2] = bb.z; ga[a][4*g+3] = bb.w;
        }
      #pragma unroll
      for (int cc = 0; cc < 8; ++cc) {
        #pragma unroll
        for (int a = 0; a < 4; ++a)
          ga[a] = __builtin_amdgcn_mfma_f32_32x32x16_bf16(
                    *reinterpret_cast<const bf16x8*>(&wcatTA[((2 * a + p) * 8 + cc) * 512 + L * 8]),
                    xfhB[cc], ga[a], 0, 0, 0);
      }
      float hq[16];
      #pragma unroll
      for (int g = 0; g < 4; ++g)
        #pragma unroll
        for (int i = 0; i < 4; ++i) {
          const int ri = 4 * g + i;
          float gi = ga[0][ri], gf = ga[1][ri], gg = ga[2][ri], go = ga[3][ri];
          float ccv = sigm(gf) * cx[p * 16 + ri] + sigm(gi) * tanh_fast(gg);
          cx[p * 16 + ri] = ccv;
          hq[ri] = sigm(go) * tanh_fast(ccv);
        }
      hN[2*p]   = cpack8(hq[0], hq[1], hq[2], hq[3], hq[4], hq[5], hq[6], hq[7]);
      hN[2*p+1] = cpack8(hq[8], hq[9], hq[10], hq[11], hq[12], hq[13], hq[14], hq[15]);
    }
    #pragma unroll
    for (int t = 0; t < 4; ++t) xfhB[4 + t] = hN[t];
    // ---- decoder: d1^T, d2^T, pred update, next-xB build (all in regs) ----
    if (de) {
      if (step == TSTEPS) {
        const float* px = xh + ((b * TSTEPS + (TSTEPS - 1)) * 32 + n5) * 11;
        if (hf == 0) { predr[0] = px[0]; predr[1] = px[1]; predr[2] = px[2]; predr[3] = px[3]; }
        else         { predr[0] = px[4]; predr[1] = px[5]; }
        st0 = px[6 + 2 * hf]; st1 = px[7 + 2 * hf]; st2 = px[10];
      }
      f32x16 cD;
      #pragma unroll
      for (int g = 0; g < 4; ++g) {
        float4 bb = *reinterpret_cast<const float4*>(&sBd1[8 * g + 4 * hf]);
        cD[4*g+0] = bb.x; cD[4*g+1] = bb.y; cD[4*g+2] = bb.z; cD[4*g+3] = bb.w;
      }
      #pragma unroll
      for (int cc = 0; cc < 4; ++cc)
        cD = __builtin_amdgcn_mfma_f32_32x32x16_bf16(
               *reinterpret_cast<const bf16x8*>(&wd1TA[cc * 512 + L * 8]), xfhB[4 + cc], cD, 0, 0, 0);
      float v[16];
      #pragma unroll
      for (int i = 0; i < 16; ++i) v[i] = fmaxf(cD[i], 0.0f);
      bf16x8 rB0 = cpack8(v[0], v[1], v[2], v[3], v[4], v[5], v[6], v[7]);
      bf16x8 rB1 = cpack8(v[8], v[9], v[10], v[11], v[12], v[13], v[14], v[15]);
      f32x16 c2;
      #pragma unroll
      for (int i = 0; i < 4; ++i) c2[i] = sBd2[4 * hf + i];
      #pragma unroll
      for (int i = 4; i < 16; ++i) c2[i] = 0.0f;
      c2 = __builtin_amdgcn_mfma_f32_32x32x16_bf16(
             *reinterpret_cast<const bf16x8*>(&wd2TA[L * 8]), rB0, c2, 0, 0, 0);
      c2 = __builtin_amdgcn_mfma_f32_32x32x16_bf16(
             *reinterpret_cast<const bf16x8*>(&wd2TA[512 + L * 8]), rB1, c2, 0, 0, 0);
      float* op = out + ((b * FUT + (step - TSTEPS)) * 32 + n5) * 6;
      if (hf == 0) {
        float p0 = predr[0] + c2[0];
        float p1 = predr[1] + c2[1];
        float p2 = predr[2] + c2[2];
        float p3 = predr[3] + c2[3];
        predr[0] = p0; predr[1] = p1; predr[2] = p2; predr[3] = p3;
        *reinterpret_cast<float2*>(op + 0) = make_float2(p0, p1);
        *reinterpret_cast<float2*>(op + 2) = make_float2(p2, p3);
      } else {
        float p4 = predr[0] + c2[0];
        float p5 = predr[1] + c2[1];
        predr[0] = p4; predr[1] = p5;
        *reinterpret_cast<float2*>(op + 4) = make_float2(p4, p5);
      }
      // next xB = [pred(6) | stat(5) | 0...] in frag layout, built in regs.
      // hf0 lane needs feats 0-7 = p0..p5,s6,s7 ; hf1 lane feats 8-15 = s8,s9,s10,0..
      uint32_t pa = pk2(predr[0], predr[1]);          // hf0:{p0,p1}  hf1:{p4,p5}
      auto sw = __builtin_amdgcn_permlane32_swap(pa, pa, false, false);
      uint32_t d0 = hf ? pk2(st0, st1)  : pa;
      uint32_t d1 = hf ? pk2(st2, 0.0f) : pk2(predr[2], predr[3]);
      uint32_t d2 = hf ? 0u : (uint32_t)sw[1];        // {p4,p5} pulled from hf1
      uint32_t d3 = hf ? 0u : pk2(st0, st1);
      union { uint32x4v u; bf16x8 h; } xo;
      xo.u = uint32x4v{d0, d1, d2, d3};
      xBcur = xo.h;
    }
  }
}

extern "C" void kernel_launch(void* const* d_in, const int* in_sizes, int n_in,
                              void* d_out, int out_size, void* d_ws, size_t ws_size,
                              hipStream_t stream) {
  (void)in_sizes; (void)n_in; (void)d_ws; (void)ws_size; (void)out_size;
  const float* xh   = (const float*)d_in[0];
  const float* adj  = (const float*)d_in[1];
  const float* Wenc = (const float*)d_in[2];
  const float* benc = (const float*)d_in[3];
  const float* Wg1  = (const float*)d_in[4];
  const float* bg1  = (const float*)d_in[5];
  const float* Wg2  = (const float*)d_in[6];
  const float* bg2  = (const float*)d_in[7];
  const float* Wih  = (const float*)d_in[8];
  const float* Whh  = (const float*)d_in[9];
  const float* bih  = (const float*)d_in[10];
  const float* bhh  = (const float*)d_in[11];
  const float* Wd1  = (const float*)d_in[12];
  const float* bd1  = (const float*)d_in[13];
  const float* Wd2  = (const float*)d_in[14];
  const float* bd2  = (const float*)d_in[15];
  float* out = (float*)d_out;
  stgnn_kernel<<<dim3(256), dim3(NT), 0, stream>>>(
      xh, adj, Wenc, benc, Wg1, bg1, Wg2, bg2,
      Wih, Whh, bih, bhh, Wd1, bd1, Wd2, bd2, out);
}

// Round 2
// 1519.613 us; speedup vs baseline: 3.9010x; 3.9010x over previous
//
#include <hip/hip_runtime.h>
#include <cstdint>

// WeatherSTGNN persistent kernel, round 7: register-resident chain, pressure-capped.
// Round 6 post-mortem: the in-register C->frag chain (cpack8: cvt_pk pairs +
// permlane32_swap, verified correct) removed all chain-LDS round trips, but the
// persistent live set + LICM-hoisted loop-invariant LDS loads blew past the
// 256-reg/wave cap -> 134MB scratch footprint -> 12.9GB HBM reload traffic.
// Fixes here:
//  1. asm volatile memory clobber per step + unroll(disable): loop-invariant
//     bias/weight LDS loads are re-read each step instead of hoisted+spilled.
//  2. Ahat hi/lo and Wenc fragments live in LDS (frag layout), loaded at use.
//  3. LSTM split: accumulate i,f,g gates (48 regs), c-update holding tanh(c),
//     then o-gate pass (16 regs). Peak accumulator 64 -> 48.
// Chain hand-offs (enc->t1->s1->t2->xf->LSTM->d1->d2) stay fully in registers.

#define NT 512
#define TSTEPS 48
#define FUT 48

typedef __bf16 bf16;
typedef __attribute__((ext_vector_type(2))) __bf16 bf16x2;
typedef __attribute__((ext_vector_type(8))) __bf16 bf16x8;
typedef __attribute__((ext_vector_type(16))) float f32x16;
typedef unsigned int uint32x4v __attribute__((ext_vector_type(4)));

__device__ __forceinline__ float sigm(float x) { return 1.0f / (1.0f + __expf(-x)); }
__device__ __forceinline__ float tanh_fast(float x) { return 1.0f - 2.0f / (__expf(2.0f * x) + 1.0f); }

__device__ __forceinline__ uint32_t pk2(float x, float y) {
  union { bf16x2 h; uint32_t u; } t;
  t.h[0] = (bf16)x; t.h[1] = (bf16)y;
  return t.u;
}

// C-regs v0..v7 (quads q,q+1 of a 32x32 C tile) -> one bf16x8 A/B-frag chunk.
// frag lanes<32 <- quad q, lanes>=32 <- quad q+1; elems 0-3 from hf=0 source
// half, 4-7 from hf=1. permlane32_swap(a,b): r[0]={a.lo,b.lo}, r[1]={a.hi,b.hi}.
__device__ __forceinline__ bf16x8 cpack8(float v0, float v1, float v2, float v3,
                                         float v4, float v5, float v6, float v7) {
  uint32_t a0 = pk2(v0, v1), a1 = pk2(v2, v3);
  uint32_t b0 = pk2(v4, v5), b1 = pk2(v6, v7);
  auto r0 = __builtin_amdgcn_permlane32_swap(a0, b0, false, false);
  auto r1 = __builtin_amdgcn_permlane32_swap(a1, b1, false, false);
  union { uint32x4v u; bf16x8 h; } o;
  o.u = uint32x4v{(uint32_t)r0[0], (uint32_t)r1[0], (uint32_t)r0[1], (uint32_t)r1[1]};
  return o.h;
}

__global__ __launch_bounds__(NT, 2)
void stgnn_kernel(const float* __restrict__ xh, const float* __restrict__ adj,
                  const float* __restrict__ Wenc, const float* __restrict__ benc,
                  const float* __restrict__ Wg1, const float* __restrict__ bg1,
                  const float* __restrict__ Wg2, const float* __restrict__ bg2,
                  const float* __restrict__ Wih, const float* __restrict__ Whh,
                  const float* __restrict__ bih, const float* __restrict__ bhh,
                  const float* __restrict__ Wd1, const float* __restrict__ bd1,
                  const float* __restrict__ Wd2, const float* __restrict__ bd2,
                  float* __restrict__ out) {
  __shared__ __align__(16) bf16 wcatTA[32768];  // Wcat^T A-frag (8 mt x 8 c)
  __shared__ __align__(16) bf16 wg1B[4096];     // Wg1 B-frag (2 nt x 4 c)
  __shared__ __align__(16) bf16 wg2B[4096];     // Wg2 B-frag
  __shared__ __align__(16) bf16 wencTA[1024];   // Wenc^T A-frag (2 mt x 1 c)
  __shared__ __align__(16) bf16 wd1TA[2048];    // Wd1^T A-frag (1 mt x 4 c)
  __shared__ __align__(16) bf16 wd2TA[1024];    // Wd2^T A-frag (1 mt x 2 c, d padded)
  __shared__ __align__(16) bf16 ahHiB[1024];    // Ahat^T hi B-frag (2 c)
  __shared__ __align__(16) bf16 ahLoB[1024];    // Ahat^T lo B-frag (2 c)
  __shared__ __align__(16) float sBenc[64];
  __shared__ __align__(16) float sBg1[64];
  __shared__ __align__(16) float sBg2[64];
  __shared__ __align__(16) float sBih[256];
  __shared__ __align__(16) float sBd1[32];
  __shared__ __align__(16) float sBd2[8];
  __shared__ float sDeg[32];
  __shared__ __align__(16) float sAh[1024];     // normalized Ahat (setup only)
  __shared__ __align__(16) bf16 sXbA[8 * 512];  // per-wave x staging, [node][f pad16]

  const int tid = threadIdx.x;
  const int L   = tid & 63;
  const int w   = tid >> 6;
  const int n5  = L & 31;
  const int hf  = L >> 5;
  const long long b = (long long)blockIdx.x * 8 + w;

  bf16* sXb = sXbA + (w << 9);

  // ---------------- static staging ----------------
  for (int i = tid; i < 1024; i += NT) {
    int f = i >> 6, h = i & 63;
    float v = (f < 11) ? Wenc[f * 64 + h] : 0.0f;
    wencTA[(h >> 5) * 512 + ((h & 31) + 32 * ((f >> 3) & 1)) * 8 + (f & 7)] = (bf16)v;
  }
  for (int i = tid; i < 4096; i += NT) {
    int k = i >> 6, n = i & 63;
    int off = (((n >> 5) * 4 + (k >> 4)) * 64 + (n & 31) + 32 * ((k >> 3) & 1)) * 8 + (k & 7);
    wg1B[off] = (bf16)Wg1[i];
    wg2B[off] = (bf16)Wg2[i];
  }
  for (int i = tid; i < 32768; i += NT) {
    int gc = i >> 7, k = i & 127;
    float v = (k < 64) ? Wih[gc * 64 + k] : Whh[gc * 64 + (k - 64)];
    wcatTA[((gc >> 5) * 8 + (k >> 4)) * 512 + ((gc & 31) + 32 * ((k >> 3) & 1)) * 8 + (k & 7)] = (bf16)v;
  }
  for (int i = tid; i < 2048; i += NT) {
    int k = i >> 5, n = i & 31;
    wd1TA[(k >> 4) * 512 + (n + 32 * ((k >> 3) & 1)) * 8 + (k & 7)] = (bf16)Wd1[k * 32 + n];
  }
  for (int i = tid; i < 1024; i += NT) {
    int k = i >> 5, d = i & 31;
    float v = (d < 6) ? Wd2[k * 6 + d] : 0.0f;
    wd2TA[(k >> 4) * 512 + (d + 32 * ((k >> 3) & 1)) * 8 + (k & 7)] = (bf16)v;
  }
  for (int i = tid; i < 64; i += NT) { sBenc[i] = benc[i]; sBg1[i] = bg1[i]; sBg2[i] = bg2[i]; }
  for (int i = tid; i < 256; i += NT) sBih[i] = bih[i] + bhh[i];
  for (int i = tid; i < 32; i += NT) sBd1[i] = bd1[i];
  if (tid < 8) sBd2[tid] = (tid < 6) ? bd2[tid] : 0.0f;
  if (tid < 32) {
    float s = 0.0f;
    for (int j = 0; j < 32; ++j) s += (j == tid) ? 1.0f : adj[tid * 32 + j];
    sDeg[tid] = 1.0f / sqrtf(fmaxf(s, 1.0f));
  }
  __syncthreads();
  for (int i = tid; i < 1024; i += NT) {
    int ii = i >> 5, jj = i & 31;
    float v = (ii == jj) ? 1.0f : adj[i];
    sAh[i] = sDeg[ii] * v * sDeg[jj];
  }
  __syncthreads();
  // Ahat hi/lo B-fragments into LDS (wave 0 covers all 64 lanes x 2 chunks)
  if (w == 0) {
    #pragma unroll
    for (int c = 0; c < 2; ++c)
      #pragma unroll
      for (int j = 0; j < 8; ++j) {
        int k = 16 * c + 8 * hf + j;
        float v = sAh[n5 * 32 + k];
        bf16 hi = (bf16)v;
        ahHiB[c * 512 + L * 8 + j] = hi;
        ahLoB[c * 512 + L * 8 + j] = (bf16)(v - (float)hi);
      }
  }
  __syncthreads();  // last barrier: everything per-wave / read-only after this

  // persistent per-wave registers (kept deliberately small)
  float cx[32];
  #pragma unroll
  for (int i = 0; i < 32; ++i) cx[i] = 0.0f;
  bf16x8 xfhB[8];
  #pragma unroll
  for (int t = 0; t < 8; ++t)
    #pragma unroll
    for (int j = 0; j < 8; ++j) xfhB[t][j] = (bf16)0.0f;
  float predr[4] = {0.f, 0.f, 0.f, 0.f};
  float st0 = 0.f, st1 = 0.f, st2 = 0.f;

  // zero-pad f>=11 forever, commit step-0 input, prefetch step-1
  for (int i = L; i < 512; i += 64) sXb[i] = (bf16)0.0f;
  float xpre[6];
  #pragma unroll
  for (int t = 0; t < 6; ++t) {
    int i = L + (t << 6);
    xpre[t] = (i < 352) ? xh[b * (TSTEPS * 352) + i] : 0.0f;
  }
  #pragma unroll
  for (int t = 0; t < 6; ++t) {
    int i = L + (t << 6);
    if (i < 352) { int j = i / 11, f = i - j * 11; sXb[(j << 4) + f] = (bf16)xpre[t]; }
  }
  #pragma unroll
  for (int t = 0; t < 6; ++t) {
    int i = L + (t << 6);
    if (i < 352) xpre[t] = xh[b * (TSTEPS * 352) + 352 + i];
  }
  bf16x8 xBcur = *reinterpret_cast<const bf16x8*>(&sXb[(n5 << 4) + (hf << 3)]);

  #pragma unroll 1
  for (int step = 0; step < TSTEPS + FUT; ++step) {
    // Anti-LICM fence: loop-invariant LDS loads (biases, weight frags) must be
    // re-issued each step instead of being hoisted into persistent registers
    // (round-6 lesson: hoisting -> 256-reg cap blown -> HBM-backed scratch).
    asm volatile("" ::: "memory");
    const bool de = (step >= TSTEPS);
    const bf16x8 xB = xBcur;  // staged/built one step ago -> no latency here
    if (!de) {
      if (step + 1 < TSTEPS) {
        #pragma unroll
        for (int t = 0; t < 6; ++t) {
          int i = L + (t << 6);
          if (i < 352) { int j = i / 11, f = i - j * 11; sXb[(j << 4) + f] = (bf16)xpre[t]; }
        }
      }
      if (step + 2 < TSTEPS) {
        #pragma unroll
        for (int t = 0; t < 6; ++t) {
          int i = L + (t << 6);
          if (i < 352) xpre[t] = xh[b * (TSTEPS * 352) + (step + 2) * 352 + i];
        }
      }
      xBcur = *reinterpret_cast<const bf16x8*>(&sXb[(n5 << 4) + (hf << 3)]);
    }
    // ---- enc^T = relu(Wenc^T @ x^T + benc), bias in acc init ----
    bf16x8 rA[4];
    #pragma unroll
    for (int mt = 0; mt < 2; ++mt) {
      f32x16 c;
      #pragma unroll
      for (int g = 0; g < 4; ++g) {
        float4 bb = *reinterpret_cast<const float4*>(&sBenc[32 * mt + 8 * g + 4 * hf]);
        c[4*g+0] = bb.x; c[4*g+1] = bb.y; c[4*g+2] = bb.z; c[4*g+3] = bb.w;
      }
      c = __builtin_amdgcn_mfma_f32_32x32x16_bf16(
            *reinterpret_cast<const bf16x8*>(&wencTA[mt * 512 + L * 8]), xB, c, 0, 0, 0);
      rA[2*mt]   = cpack8(fmaxf(c[0], 0.f), fmaxf(c[1], 0.f), fmaxf(c[2], 0.f), fmaxf(c[3], 0.f),
                          fmaxf(c[4], 0.f), fmaxf(c[5], 0.f), fmaxf(c[6], 0.f), fmaxf(c[7], 0.f));
      rA[2*mt+1] = cpack8(fmaxf(c[8], 0.f), fmaxf(c[9], 0.f), fmaxf(c[10], 0.f), fmaxf(c[11], 0.f),
                          fmaxf(c[12], 0.f), fmaxf(c[13], 0.f), fmaxf(c[14], 0.f), fmaxf(c[15], 0.f));
    }
    // ---- t1 = enc @ Wg1 ----
    bf16x8 nA[4];
    #pragma unroll
    for (int nt = 0; nt < 2; ++nt) {
      f32x16 c;
      #pragma unroll
      for (int i = 0; i < 16; ++i) c[i] = 0.0f;
      #pragma unroll
      for (int cc = 0; cc < 4; ++cc)
        c = __builtin_amdgcn_mfma_f32_32x32x16_bf16(rA[cc],
              *reinterpret_cast<const bf16x8*>(&wg1B[(nt * 4 + cc) * 512 + L * 8]), c, 0, 0, 0);
      nA[2*nt]   = cpack8(c[0], c[1], c[2], c[3], c[4], c[5], c[6], c[7]);
      nA[2*nt+1] = cpack8(c[8], c[9], c[10], c[11], c[12], c[13], c[14], c[15]);
    }
    // ---- s1^T = relu(t1^T @ Ahat^T + bg1) ----
    {
      bf16x8 aH0 = *reinterpret_cast<const bf16x8*>(&ahHiB[L * 8]);
      bf16x8 aL0 = *reinterpret_cast<const bf16x8*>(&ahLoB[L * 8]);
      bf16x8 aH1 = *reinterpret_cast<const bf16x8*>(&ahHiB[512 + L * 8]);
      bf16x8 aL1 = *reinterpret_cast<const bf16x8*>(&ahLoB[512 + L * 8]);
      #pragma unroll
      for (int mt = 0; mt < 2; ++mt) {
        f32x16 c;
        #pragma unroll
        for (int g = 0; g < 4; ++g) {
          float4 bb = *reinterpret_cast<const float4*>(&sBg1[32 * mt + 8 * g + 4 * hf]);
          c[4*g+0] = bb.x; c[4*g+1] = bb.y; c[4*g+2] = bb.z; c[4*g+3] = bb.w;
        }
        c = __builtin_amdgcn_mfma_f32_32x32x16_bf16(nA[mt * 2 + 0], aH0, c, 0, 0, 0);
        c = __builtin_amdgcn_mfma_f32_32x32x16_bf16(nA[mt * 2 + 0], aL0, c, 0, 0, 0);
        c = __builtin_amdgcn_mfma_f32_32x32x16_bf16(nA[mt * 2 + 1], aH1, c, 0, 0, 0);
        c = __builtin_amdgcn_mfma_f32_32x32x16_bf16(nA[mt * 2 + 1], aL1, c, 0, 0, 0);
        rA[2*mt]   = cpack8(fmaxf(c[0], 0.f), fmaxf(c[1], 0.f), fmaxf(c[2], 0.f), fmaxf(c[3], 0.f),
                            fmaxf(c[4], 0.f), fmaxf(c[5], 0.f), fmaxf(c[6], 0.f), fmaxf(c[7], 0.f));
        rA[2*mt+1] = cpack8(fmaxf(c[8], 0.f), fmaxf(c[9], 0.f), fmaxf(c[10], 0.f), fmaxf(c[11], 0.f),
                            fmaxf(c[12], 0.f), fmaxf(c[13], 0.f), fmaxf(c[14], 0.f), fmaxf(c[15], 0.f));
      }
    }
    // ---- t2 = s1 @ Wg2 ----
    #pragma unroll
    for (int nt = 0; nt < 2; ++nt) {
      f32x16 c;
      #pragma unroll
      for (int i = 0; i < 16; ++i) c[i] = 0.0f;
      #pragma unroll
      for (int cc = 0; cc < 4; ++cc)
        c = __builtin_amdgcn_mfma_f32_32x32x16_bf16(rA[cc],
              *reinterpret_cast<const bf16x8*>(&wg2B[(nt * 4 + cc) * 512 + L * 8]), c, 0, 0, 0);
      nA[2*nt]   = cpack8(c[0], c[1], c[2], c[3], c[4], c[5], c[6], c[7]);
      nA[2*nt+1] = cpack8(c[8], c[9], c[10], c[11], c[12], c[13], c[14], c[15]);
    }
    // ---- xf^T = relu(t2^T @ Ahat^T + bg2) -> xfhB[0..3] ----
    {
      bf16x8 aH0 = *reinterpret_cast<const bf16x8*>(&ahHiB[L * 8]);
      bf16x8 aL0 = *reinterpret_cast<const bf16x8*>(&ahLoB[L * 8]);
      bf16x8 aH1 = *reinterpret_cast<const bf16x8*>(&ahHiB[512 + L * 8]);
      bf16x8 aL1 = *reinterpret_cast<const bf16x8*>(&ahLoB[512 + L * 8]);
      #pragma unroll
      for (int mt = 0; mt < 2; ++mt) {
        f32x16 c;
        #pragma unroll
        for (int g = 0; g < 4; ++g) {
          float4 bb = *reinterpret_cast<const float4*>(&sBg2[32 * mt + 8 * g + 4 * hf]);
          c[4*g+0] = bb.x; c[4*g+1] = bb.y; c[4*g+2] = bb.z; c[4*g+3] = bb.w;
        }
        c = __builtin_amdgcn_mfma_f32_32x32x16_bf16(nA[mt * 2 + 0], aH0, c, 0, 0, 0);
        c = __builtin_amdgcn_mfma_f32_32x32x16_bf16(nA[mt * 2 + 0], aL0, c, 0, 0, 0);
        c = __builtin_amdgcn_mfma_f32_32x32x16_bf16(nA[mt * 2 + 1], aH1, c, 0, 0, 0);
        c = __builtin_amdgcn_mfma_f32_32x32x16_bf16(nA[mt * 2 + 1], aL1, c, 0, 0, 0);
        xfhB[2*mt]   = cpack8(fmaxf(c[0], 0.f), fmaxf(c[1], 0.f), fmaxf(c[2], 0.f), fmaxf(c[3], 0.f),
                              fmaxf(c[4], 0.f), fmaxf(c[5], 0.f), fmaxf(c[6], 0.f), fmaxf(c[7], 0.f));
        xfhB[2*mt+1] = cpack8(fmaxf(c[8], 0.f), fmaxf(c[9], 0.f), fmaxf(c[10], 0.f), fmaxf(c[11], 0.f),
                              fmaxf(c[12], 0.f), fmaxf(c[13], 0.f), fmaxf(c[14], 0.f), fmaxf(c[15], 0.f));
      }
    }
    // ---- LSTM, split gates: {i,f,g} accumulate -> c update -> {o} -> h ----
    bf16x8 hN[4];
    #pragma unroll
    for (int p = 0; p < 2; ++p) {
      f32x16 gI, gF, gG;
      #pragma unroll
      for (int g = 0; g < 4; ++g) {
        float4 bI = *reinterpret_cast<const float4*>(&sBih[      32 * p + 8 * g + 4 * hf]);
        float4 bF = *reinterpret_cast<const float4*>(&sBih[ 64 + 32 * p + 8 * g + 4 * hf]);
        float4 bG = *reinterpret_cast<const float4*>(&sBih[128 + 32 * p + 8 * g + 4 * hf]);
        gI[4*g+0]=bI.x; gI[4*g+1]=bI.y; gI[4*g+2]=bI.z; gI[4*g+3]=bI.w;
        gF[4*g+0]=bF.x; gF[4*g+1]=bF.y; gF[4*g+2]=bF.z; gF[4*g+3]=bF.w;
        gG[4*g+0]=bG.x; gG[4*g+1]=bG.y; gG[4*g+2]=bG.z; gG[4*g+3]=bG.w;
      }
      #pragma unroll
      for (int cc = 0; cc < 8; ++cc) {
        gI = __builtin_amdgcn_mfma_f32_32x32x16_bf16(
               *reinterpret_cast<const bf16x8*>(&wcatTA[((0 + p) * 8 + cc) * 512 + L * 8]),
               xfhB[cc], gI, 0, 0, 0);
        gF = __builtin_amdgcn_mfma_f32_32x32x16_bf16(
               *reinterpret_cast<const bf16x8*>(&wcatTA[((2 + p) * 8 + cc) * 512 + L * 8]),
               xfhB[cc], gF, 0, 0, 0);
        gG = __builtin_amdgcn_mfma_f32_32x32x16_bf16(
               *reinterpret_cast<const bf16x8*>(&wcatTA[((4 + p) * 8 + cc) * 512 + L * 8]),
               xfhB[cc], gG, 0, 0, 0);
      }
      float tc[16];
      #pragma unroll
      for (int ri = 0; ri < 16; ++ri) {
        float ccv = sigm(gF[ri]) * cx[p * 16 + ri] + sigm(gI[ri]) * tanh_fast(gG[ri]);
        cx[p * 16 + ri] = ccv;
        tc[ri] = tanh_fast(ccv);
      }
      f32x16 gO;
      #pragma unroll
      for (int g = 0; g < 4; ++g) {
        float4 bO = *reinterpret_cast<const float4*>(&sBih[192 + 32 * p + 8 * g + 4 * hf]);
        gO[4*g+0]=bO.x; gO[4*g+1]=bO.y; gO[4*g+2]=bO.z; gO[4*g+3]=bO.w;
      }
      #pragma unroll
      for (int cc = 0; cc < 8; ++cc)
        gO = __builtin_amdgcn_mfma_f32_32x32x16_bf16(
               *reinterpret_cast<const bf16x8*>(&wcatTA[((6 + p) * 8 + cc) * 512 + L * 8]),
               xfhB[cc], gO, 0, 0, 0);
      float hq[16];
      #pragma unroll
      for (int ri = 0; ri < 16; ++ri) hq[ri] = sigm(gO[ri]) * tc[ri];
      hN[2*p]   = cpack8(hq[0], hq[1], hq[2], hq[3], hq[4], hq[5], hq[6], hq[7]);
      hN[2*p+1] = cpack8(hq[8], hq[9], hq[10], hq[11], hq[12], hq[13], hq[14], hq[15]);
    }
    #pragma unroll
    for (int t = 0; t < 4; ++t) xfhB[4 + t] = hN[t];
    // ---- decoder: d1^T, d2^T, pred update, next-xB build (all in regs) ----
    if (de) {
      if (step == TSTEPS) {
        const float* px = xh + ((b * TSTEPS + (TSTEPS - 1)) * 32 + n5) * 11;
        if (hf == 0) { predr[0] = px[0]; predr[1] = px[1]; predr[2] = px[2]; predr[3] = px[3]; }
        else         { predr[0] = px[4]; predr[1] = px[5]; }
        st0 = px[6 + 2 * hf]; st1 = px[7 + 2 * hf]; st2 = px[10];
      }
      f32x16 cD;
      #pragma unroll
      for (int g = 0; g < 4; ++g) {
        float4 bb = *reinterpret_cast<const float4*>(&sBd1[8 * g + 4 * hf]);
        cD[4*g+0] = bb.x; cD[4*g+1] = bb.y; cD[4*g+2] = bb.z; cD[4*g+3] = bb.w;
      }
      #pragma unroll
      for (int cc = 0; cc < 4; ++cc)
        cD = __builtin_amdgcn_mfma_f32_32x32x16_bf16(
               *reinterpret_cast<const bf16x8*>(&wd1TA[cc * 512 + L * 8]), xfhB[4 + cc], cD, 0, 0, 0);
      bf16x8 rB0 = cpack8(fmaxf(cD[0], 0.f), fmaxf(cD[1], 0.f), fmaxf(cD[2], 0.f), fmaxf(cD[3], 0.f),
                          fmaxf(cD[4], 0.f), fmaxf(cD[5], 0.f), fmaxf(cD[6], 0.f), fmaxf(cD[7], 0.f));
      bf16x8 rB1 = cpack8(fmaxf(cD[8], 0.f), fmaxf(cD[9], 0.f), fmaxf(cD[10], 0.f), fmaxf(cD[11], 0.f),
                          fmaxf(cD[12], 0.f), fmaxf(cD[13], 0.f), fmaxf(cD[14], 0.f), fmaxf(cD[15], 0.f));
      f32x16 c2;
      #pragma unroll
      for (int i = 0; i < 4; ++i) c2[i] = sBd2[4 * hf + i];
      #pragma unroll
      for (int i = 4; i < 16; ++i) c2[i] = 0.0f;
      c2 = __builtin_amdgcn_mfma_f32_32x32x16_bf16(
             *reinterpret_cast<const bf16x8*>(&wd2TA[L * 8]), rB0, c2, 0, 0, 0);
      c2 = __builtin_amdgcn_mfma_f32_32x32x16_bf16(
             *reinterpret_cast<const bf16x8*>(&wd2TA[512 + L * 8]), rB1, c2, 0, 0, 0);
      float* op = out + ((b * FUT + (step - TSTEPS)) * 32 + n5) * 6;
      if (hf == 0) {
        float p0 = predr[0] + c2[0];
        float p1 = predr[1] + c2[1];
        float p2 = predr[2] + c2[2];
        float p3 = predr[3] + c2[3];
        predr[0] = p0; predr[1] = p1; predr[2] = p2; predr[3] = p3;
        *reinterpret_cast<float2*>(op + 0) = make_float2(p0, p1);
        *reinterpret_cast<float2*>(op + 2) = make_float2(p2, p3);
      } else {
        float p4 = predr[0] + c2[0];
        float p5 = predr[1] + c2[1];
        predr[0] = p4; predr[1] = p5;
        *reinterpret_cast<float2*>(op + 4) = make_float2(p4, p5);
      }
      // next xB = [pred(6) | stat(5) | 0...] in frag layout, built in regs.
      uint32_t pa = pk2(predr[0], predr[1]);          // hf0:{p0,p1}  hf1:{p4,p5}
      auto sw = __builtin_amdgcn_permlane32_swap(pa, pa, false, false);
      uint32_t d0 = hf ? pk2(st0, st1)  : pa;
      uint32_t d1 = hf ? pk2(st2, 0.0f) : pk2(predr[2], predr[3]);
      uint32_t d2 = hf ? 0u : (uint32_t)sw[1];        // {p4,p5} pulled from hf1
      uint32_t d3 = hf ? 0u : pk2(st0, st1);
      union { uint32x4v u; bf16x8 h; } xo;
      xo.u = uint32x4v{d0, d1, d2, d3};
      xBcur = xo.h;
    }
  }
}

extern "C" void kernel_launch(void* const* d_in, const int* in_sizes, int n_in,
                              void* d_out, int out_size, void* d_ws, size_t ws_size,
                              hipStream_t stream) {
  (void)in_sizes; (void)n_in; (void)d_ws; (void)ws_size; (void)out_size;
  const float* xh   = (const float*)d_in[0];
  const float* adj  = (const float*)d_in[1];
  const float* Wenc = (const float*)d_in[2];
  const float* benc = (const float*)d_in[3];
  const float* Wg1  = (const float*)d_in[4];
  const float* bg1  = (const float*)d_in[5];
  const float* Wg2  = (const float*)d_in[6];
  const float* bg2  = (const float*)d_in[7];
  const float* Wih  = (const float*)d_in[8];
  const float* Whh  = (const float*)d_in[9];
  const float* bih  = (const float*)d_in[10];
  const float* bhh  = (const float*)d_in[11];
  const float* Wd1  = (const float*)d_in[12];
  const float* bd1  = (const float*)d_in[13];
  const float* Wd2  = (const float*)d_in[14];
  const float* bd2  = (const float*)d_in[15];
  float* out = (float*)d_out;
  stgnn_kernel<<<dim3(256), dim3(NT), 0, stream>>>(
      xh, adj, Wenc, benc, Wg1, bg1, Wg2, bg2,
      Wih, Whh, bih, bhh, Wd1, bd1, Wd2, bd2, out);
}

// Round 3
// 1041.247 us; speedup vs baseline: 5.6932x; 1.4594x over previous
//
#include <hip/hip_runtime.h>
#include <cstdint>

// WeatherSTGNN persistent kernel, round 8: fast activations + selective hoist.
// Round 7 post-mortem: removing the whole chain-LDS structure (r5->r7) changed
// dur by only -3% with VALUBusy pinned at ~76 -> the limiter is the VALU
// instruction stream itself, dominated by IEEE float divides in sigm/tanh
// (160 divides + 160 exps per wave-step, ~8-10 insts + ~30cyc latency each).
// Changes vs round 7:
//  1. sigm/tanh via v_rcp_f32 (__builtin_amdgcn_rcpf) + v_exp_f32
//     (__builtin_amdgcn_exp2f with folded log2e): 4-5 insts instead of ~10-12
//     with no div_scale/div_fixup chains. ~1ulp rcp error << bf16 rounding.
//  2. Ahat hi/lo B-frags + Wenc A-frags hoisted to persistent registers
//     (+24 regs, peak ~210 < 256; round-6 disaster was blanket LICM hoisting,
//     this is a controlled 24-reg hoist). Removes 10 chain-head ds_reads/step.
// Everything else identical to round 7 (register-resident chain, cpack8,
// anti-LICM fence, bias-in-acc-init, zero barriers in the 96-step loop).

#define NT 512
#define TSTEPS 48
#define FUT 48

typedef __bf16 bf16;
typedef __attribute__((ext_vector_type(2))) __bf16 bf16x2;
typedef __attribute__((ext_vector_type(8))) __bf16 bf16x8;
typedef __attribute__((ext_vector_type(16))) float f32x16;
typedef unsigned int uint32x4v __attribute__((ext_vector_type(4)));

// sigm(x) = 1/(1+exp(-x)) = rcp(1 + exp2(-x*log2e))
__device__ __forceinline__ float sigm(float x) {
  return __builtin_amdgcn_rcpf(1.0f + __builtin_amdgcn_exp2f(x * -1.442695041f));
}
// tanh(x) = 1 - 2/(exp(2x)+1) = fma(-2, rcp(1 + exp2(x*2*log2e)), 1)
__device__ __forceinline__ float tanh_fast(float x) {
  return __builtin_fmaf(-2.0f,
           __builtin_amdgcn_rcpf(1.0f + __builtin_amdgcn_exp2f(x * 2.885390082f)),
           1.0f);
}

__device__ __forceinline__ uint32_t pk2(float x, float y) {
  union { bf16x2 h; uint32_t u; } t;
  t.h[0] = (bf16)x; t.h[1] = (bf16)y;
  return t.u;
}

// C-regs v0..v7 (quads q,q+1 of a 32x32 C tile) -> one bf16x8 A/B-frag chunk.
// frag lanes<32 <- quad q, lanes>=32 <- quad q+1; elems 0-3 from hf=0 source
// half, 4-7 from hf=1. permlane32_swap(a,b): r[0]={a.lo,b.lo}, r[1]={a.hi,b.hi}.
__device__ __forceinline__ bf16x8 cpack8(float v0, float v1, float v2, float v3,
                                         float v4, float v5, float v6, float v7) {
  uint32_t a0 = pk2(v0, v1), a1 = pk2(v2, v3);
  uint32_t b0 = pk2(v4, v5), b1 = pk2(v6, v7);
  auto r0 = __builtin_amdgcn_permlane32_swap(a0, b0, false, false);
  auto r1 = __builtin_amdgcn_permlane32_swap(a1, b1, false, false);
  union { uint32x4v u; bf16x8 h; } o;
  o.u = uint32x4v{(uint32_t)r0[0], (uint32_t)r1[0], (uint32_t)r0[1], (uint32_t)r1[1]};
  return o.h;
}

__global__ __launch_bounds__(NT, 2)
void stgnn_kernel(const float* __restrict__ xh, const float* __restrict__ adj,
                  const float* __restrict__ Wenc, const float* __restrict__ benc,
                  const float* __restrict__ Wg1, const float* __restrict__ bg1,
                  const float* __restrict__ Wg2, const float* __restrict__ bg2,
                  const float* __restrict__ Wih, const float* __restrict__ Whh,
                  const float* __restrict__ bih, const float* __restrict__ bhh,
                  const float* __restrict__ Wd1, const float* __restrict__ bd1,
                  const float* __restrict__ Wd2, const float* __restrict__ bd2,
                  float* __restrict__ out) {
  __shared__ __align__(16) bf16 wcatTA[32768];  // Wcat^T A-frag (8 mt x 8 c)
  __shared__ __align__(16) bf16 wg1B[4096];     // Wg1 B-frag (2 nt x 4 c)
  __shared__ __align__(16) bf16 wg2B[4096];     // Wg2 B-frag
  __shared__ __align__(16) bf16 wencTA[1024];   // Wenc^T A-frag (2 mt x 1 c)
  __shared__ __align__(16) bf16 wd1TA[2048];    // Wd1^T A-frag (1 mt x 4 c)
  __shared__ __align__(16) bf16 wd2TA[1024];    // Wd2^T A-frag (1 mt x 2 c, d padded)
  __shared__ __align__(16) bf16 ahHiB[1024];    // Ahat^T hi B-frag (2 c)
  __shared__ __align__(16) bf16 ahLoB[1024];    // Ahat^T lo B-frag (2 c)
  __shared__ __align__(16) float sBenc[64];
  __shared__ __align__(16) float sBg1[64];
  __shared__ __align__(16) float sBg2[64];
  __shared__ __align__(16) float sBih[256];
  __shared__ __align__(16) float sBd1[32];
  __shared__ __align__(16) float sBd2[8];
  __shared__ float sDeg[32];
  __shared__ __align__(16) float sAh[1024];     // normalized Ahat (setup only)
  __shared__ __align__(16) bf16 sXbA[8 * 512];  // per-wave x staging, [node][f pad16]

  const int tid = threadIdx.x;
  const int L   = tid & 63;
  const int w   = tid >> 6;
  const int n5  = L & 31;
  const int hf  = L >> 5;
  const long long b = (long long)blockIdx.x * 8 + w;

  bf16* sXb = sXbA + (w << 9);

  // ---------------- static staging ----------------
  for (int i = tid; i < 1024; i += NT) {
    int f = i >> 6, h = i & 63;
    float v = (f < 11) ? Wenc[f * 64 + h] : 0.0f;
    wencTA[(h >> 5) * 512 + ((h & 31) + 32 * ((f >> 3) & 1)) * 8 + (f & 7)] = (bf16)v;
  }
  for (int i = tid; i < 4096; i += NT) {
    int k = i >> 6, n = i & 63;
    int off = (((n >> 5) * 4 + (k >> 4)) * 64 + (n & 31) + 32 * ((k >> 3) & 1)) * 8 + (k & 7);
    wg1B[off] = (bf16)Wg1[i];
    wg2B[off] = (bf16)Wg2[i];
  }
  for (int i = tid; i < 32768; i += NT) {
    int gc = i >> 7, k = i & 127;
    float v = (k < 64) ? Wih[gc * 64 + k] : Whh[gc * 64 + (k - 64)];
    wcatTA[((gc >> 5) * 8 + (k >> 4)) * 512 + ((gc & 31) + 32 * ((k >> 3) & 1)) * 8 + (k & 7)] = (bf16)v;
  }
  for (int i = tid; i < 2048; i += NT) {
    int k = i >> 5, n = i & 31;
    wd1TA[(k >> 4) * 512 + (n + 32 * ((k >> 3) & 1)) * 8 + (k & 7)] = (bf16)Wd1[k * 32 + n];
  }
  for (int i = tid; i < 1024; i += NT) {
    int k = i >> 5, d = i & 31;
    float v = (d < 6) ? Wd2[k * 6 + d] : 0.0f;
    wd2TA[(k >> 4) * 512 + (d + 32 * ((k >> 3) & 1)) * 8 + (k & 7)] = (bf16)v;
  }
  for (int i = tid; i < 64; i += NT) { sBenc[i] = benc[i]; sBg1[i] = bg1[i]; sBg2[i] = bg2[i]; }
  for (int i = tid; i < 256; i += NT) sBih[i] = bih[i] + bhh[i];
  for (int i = tid; i < 32; i += NT) sBd1[i] = bd1[i];
  if (tid < 8) sBd2[tid] = (tid < 6) ? bd2[tid] : 0.0f;
  if (tid < 32) {
    float s = 0.0f;
    for (int j = 0; j < 32; ++j) s += (j == tid) ? 1.0f : adj[tid * 32 + j];
    sDeg[tid] = 1.0f / sqrtf(fmaxf(s, 1.0f));
  }
  __syncthreads();
  for (int i = tid; i < 1024; i += NT) {
    int ii = i >> 5, jj = i & 31;
    float v = (ii == jj) ? 1.0f : adj[i];
    sAh[i] = sDeg[ii] * v * sDeg[jj];
  }
  __syncthreads();
  // Ahat hi/lo B-fragments into LDS (wave 0 covers all 64 lanes x 2 chunks)
  if (w == 0) {
    #pragma unroll
    for (int c = 0; c < 2; ++c)
      #pragma unroll
      for (int j = 0; j < 8; ++j) {
        int k = 16 * c + 8 * hf + j;
        float v = sAh[n5 * 32 + k];
        bf16 hi = (bf16)v;
        ahHiB[c * 512 + L * 8 + j] = hi;
        ahLoB[c * 512 + L * 8 + j] = (bf16)(v - (float)hi);
      }
  }
  __syncthreads();  // last barrier: everything per-wave / read-only after this

  // controlled hoist: Ahat hi/lo + Wenc fragments persistent in registers
  // (+24 regs; named locals survive the per-step "memory" clobber).
  const bf16x8 aH0 = *reinterpret_cast<const bf16x8*>(&ahHiB[L * 8]);
  const bf16x8 aL0 = *reinterpret_cast<const bf16x8*>(&ahLoB[L * 8]);
  const bf16x8 aH1 = *reinterpret_cast<const bf16x8*>(&ahHiB[512 + L * 8]);
  const bf16x8 aL1 = *reinterpret_cast<const bf16x8*>(&ahLoB[512 + L * 8]);
  const bf16x8 wencR0 = *reinterpret_cast<const bf16x8*>(&wencTA[L * 8]);
  const bf16x8 wencR1 = *reinterpret_cast<const bf16x8*>(&wencTA[512 + L * 8]);

  // persistent per-wave registers (kept deliberately small)
  float cx[32];
  #pragma unroll
  for (int i = 0; i < 32; ++i) cx[i] = 0.0f;
  bf16x8 xfhB[8];
  #pragma unroll
  for (int t = 0; t < 8; ++t)
    #pragma unroll
    for (int j = 0; j < 8; ++j) xfhB[t][j] = (bf16)0.0f;
  float predr[4] = {0.f, 0.f, 0.f, 0.f};
  float st0 = 0.f, st1 = 0.f, st2 = 0.f;

  // zero-pad f>=11 forever, commit step-0 input, prefetch step-1
  for (int i = L; i < 512; i += 64) sXb[i] = (bf16)0.0f;
  float xpre[6];
  #pragma unroll
  for (int t = 0; t < 6; ++t) {
    int i = L + (t << 6);
    xpre[t] = (i < 352) ? xh[b * (TSTEPS * 352) + i] : 0.0f;
  }
  #pragma unroll
  for (int t = 0; t < 6; ++t) {
    int i = L + (t << 6);
    if (i < 352) { int j = i / 11, f = i - j * 11; sXb[(j << 4) + f] = (bf16)xpre[t]; }
  }
  #pragma unroll
  for (int t = 0; t < 6; ++t) {
    int i = L + (t << 6);
    if (i < 352) xpre[t] = xh[b * (TSTEPS * 352) + 352 + i];
  }
  bf16x8 xBcur = *reinterpret_cast<const bf16x8*>(&sXb[(n5 << 4) + (hf << 3)]);

  #pragma unroll 1
  for (int step = 0; step < TSTEPS + FUT; ++step) {
    // Anti-LICM fence: loop-invariant LDS loads (biases, weight frags) must be
    // re-issued each step instead of being hoisted into persistent registers
    // (round-6 lesson: hoisting everything -> 256-reg cap blown -> scratch).
    asm volatile("" ::: "memory");
    const bool de = (step >= TSTEPS);
    const bf16x8 xB = xBcur;  // staged/built one step ago -> no latency here
    if (!de) {
      if (step + 1 < TSTEPS) {
        #pragma unroll
        for (int t = 0; t < 6; ++t) {
          int i = L + (t << 6);
          if (i < 352) { int j = i / 11, f = i - j * 11; sXb[(j << 4) + f] = (bf16)xpre[t]; }
        }
      }
      if (step + 2 < TSTEPS) {
        #pragma unroll
        for (int t = 0; t < 6; ++t) {
          int i = L + (t << 6);
          if (i < 352) xpre[t] = xh[b * (TSTEPS * 352) + (step + 2) * 352 + i];
        }
      }
      xBcur = *reinterpret_cast<const bf16x8*>(&sXb[(n5 << 4) + (hf << 3)]);
    }
    // ---- enc^T = relu(Wenc^T @ x^T + benc), bias in acc init ----
    bf16x8 rA[4];
    #pragma unroll
    for (int mt = 0; mt < 2; ++mt) {
      f32x16 c;
      #pragma unroll
      for (int g = 0; g < 4; ++g) {
        float4 bb = *reinterpret_cast<const float4*>(&sBenc[32 * mt + 8 * g + 4 * hf]);
        c[4*g+0] = bb.x; c[4*g+1] = bb.y; c[4*g+2] = bb.z; c[4*g+3] = bb.w;
      }
      c = __builtin_amdgcn_mfma_f32_32x32x16_bf16(mt ? wencR1 : wencR0, xB, c, 0, 0, 0);
      rA[2*mt]   = cpack8(fmaxf(c[0], 0.f), fmaxf(c[1], 0.f), fmaxf(c[2], 0.f), fmaxf(c[3], 0.f),
                          fmaxf(c[4], 0.f), fmaxf(c[5], 0.f), fmaxf(c[6], 0.f), fmaxf(c[7], 0.f));
      rA[2*mt+1] = cpack8(fmaxf(c[8], 0.f), fmaxf(c[9], 0.f), fmaxf(c[10], 0.f), fmaxf(c[11], 0.f),
                          fmaxf(c[12], 0.f), fmaxf(c[13], 0.f), fmaxf(c[14], 0.f), fmaxf(c[15], 0.f));
    }
    // ---- t1 = enc @ Wg1 ----
    bf16x8 nA[4];
    #pragma unroll
    for (int nt = 0; nt < 2; ++nt) {
      f32x16 c;
      #pragma unroll
      for (int i = 0; i < 16; ++i) c[i] = 0.0f;
      #pragma unroll
      for (int cc = 0; cc < 4; ++cc)
        c = __builtin_amdgcn_mfma_f32_32x32x16_bf16(rA[cc],
              *reinterpret_cast<const bf16x8*>(&wg1B[(nt * 4 + cc) * 512 + L * 8]), c, 0, 0, 0);
      nA[2*nt]   = cpack8(c[0], c[1], c[2], c[3], c[4], c[5], c[6], c[7]);
      nA[2*nt+1] = cpack8(c[8], c[9], c[10], c[11], c[12], c[13], c[14], c[15]);
    }
    // ---- s1^T = relu(t1^T @ Ahat^T + bg1) ----
    #pragma unroll
    for (int mt = 0; mt < 2; ++mt) {
      f32x16 c;
      #pragma unroll
      for (int g = 0; g < 4; ++g) {
        float4 bb = *reinterpret_cast<const float4*>(&sBg1[32 * mt + 8 * g + 4 * hf]);
        c[4*g+0] = bb.x; c[4*g+1] = bb.y; c[4*g+2] = bb.z; c[4*g+3] = bb.w;
      }
      c = __builtin_amdgcn_mfma_f32_32x32x16_bf16(nA[mt * 2 + 0], aH0, c, 0, 0, 0);
      c = __builtin_amdgcn_mfma_f32_32x32x16_bf16(nA[mt * 2 + 0], aL0, c, 0, 0, 0);
      c = __builtin_amdgcn_mfma_f32_32x32x16_bf16(nA[mt * 2 + 1], aH1, c, 0, 0, 0);
      c = __builtin_amdgcn_mfma_f32_32x32x16_bf16(nA[mt * 2 + 1], aL1, c, 0, 0, 0);
      rA[2*mt]   = cpack8(fmaxf(c[0], 0.f), fmaxf(c[1], 0.f), fmaxf(c[2], 0.f), fmaxf(c[3], 0.f),
                          fmaxf(c[4], 0.f), fmaxf(c[5], 0.f), fmaxf(c[6], 0.f), fmaxf(c[7], 0.f));
      rA[2*mt+1] = cpack8(fmaxf(c[8], 0.f), fmaxf(c[9], 0.f), fmaxf(c[10], 0.f), fmaxf(c[11], 0.f),
                          fmaxf(c[12], 0.f), fmaxf(c[13], 0.f), fmaxf(c[14], 0.f), fmaxf(c[15], 0.f));
    }
    // ---- t2 = s1 @ Wg2 ----
    #pragma unroll
    for (int nt = 0; nt < 2; ++nt) {
      f32x16 c;
      #pragma unroll
      for (int i = 0; i < 16; ++i) c[i] = 0.0f;
      #pragma unroll
      for (int cc = 0; cc < 4; ++cc)
        c = __builtin_amdgcn_mfma_f32_32x32x16_bf16(rA[cc],
              *reinterpret_cast<const bf16x8*>(&wg2B[(nt * 4 + cc) * 512 + L * 8]), c, 0, 0, 0);
      nA[2*nt]   = cpack8(c[0], c[1], c[2], c[3], c[4], c[5], c[6], c[7]);
      nA[2*nt+1] = cpack8(c[8], c[9], c[10], c[11], c[12], c[13], c[14], c[15]);
    }
    // ---- xf^T = relu(t2^T @ Ahat^T + bg2) -> xfhB[0..3] ----
    #pragma unroll
    for (int mt = 0; mt < 2; ++mt) {
      f32x16 c;
      #pragma unroll
      for (int g = 0; g < 4; ++g) {
        float4 bb = *reinterpret_cast<const float4*>(&sBg2[32 * mt + 8 * g + 4 * hf]);
        c[4*g+0] = bb.x; c[4*g+1] = bb.y; c[4*g+2] = bb.z; c[4*g+3] = bb.w;
      }
      c = __builtin_amdgcn_mfma_f32_32x32x16_bf16(nA[mt * 2 + 0], aH0, c, 0, 0, 0);
      c = __builtin_amdgcn_mfma_f32_32x32x16_bf16(nA[mt * 2 + 0], aL0, c, 0, 0, 0);
      c = __builtin_amdgcn_mfma_f32_32x32x16_bf16(nA[mt * 2 + 1], aH1, c, 0, 0, 0);
      c = __builtin_amdgcn_mfma_f32_32x32x16_bf16(nA[mt * 2 + 1], aL1, c, 0, 0, 0);
      xfhB[2*mt]   = cpack8(fmaxf(c[0], 0.f), fmaxf(c[1], 0.f), fmaxf(c[2], 0.f), fmaxf(c[3], 0.f),
                            fmaxf(c[4], 0.f), fmaxf(c[5], 0.f), fmaxf(c[6], 0.f), fmaxf(c[7], 0.f));
      xfhB[2*mt+1] = cpack8(fmaxf(c[8], 0.f), fmaxf(c[9], 0.f), fmaxf(c[10], 0.f), fmaxf(c[11], 0.f),
                            fmaxf(c[12], 0.f), fmaxf(c[13], 0.f), fmaxf(c[14], 0.f), fmaxf(c[15], 0.f));
    }
    // ---- LSTM, split gates: {i,f,g} accumulate -> c update -> {o} -> h ----
    bf16x8 hN[4];
    #pragma unroll
    for (int p = 0; p < 2; ++p) {
      f32x16 gI, gF, gG;
      #pragma unroll
      for (int g = 0; g < 4; ++g) {
        float4 bI = *reinterpret_cast<const float4*>(&sBih[      32 * p + 8 * g + 4 * hf]);
        float4 bF = *reinterpret_cast<const float4*>(&sBih[ 64 + 32 * p + 8 * g + 4 * hf]);
        float4 bG = *reinterpret_cast<const float4*>(&sBih[128 + 32 * p + 8 * g + 4 * hf]);
        gI[4*g+0]=bI.x; gI[4*g+1]=bI.y; gI[4*g+2]=bI.z; gI[4*g+3]=bI.w;
        gF[4*g+0]=bF.x; gF[4*g+1]=bF.y; gF[4*g+2]=bF.z; gF[4*g+3]=bF.w;
        gG[4*g+0]=bG.x; gG[4*g+1]=bG.y; gG[4*g+2]=bG.z; gG[4*g+3]=bG.w;
      }
      #pragma unroll
      for (int cc = 0; cc < 8; ++cc) {
        gI = __builtin_amdgcn_mfma_f32_32x32x16_bf16(
               *reinterpret_cast<const bf16x8*>(&wcatTA[((0 + p) * 8 + cc) * 512 + L * 8]),
               xfhB[cc], gI, 0, 0, 0);
        gF = __builtin_amdgcn_mfma_f32_32x32x16_bf16(
               *reinterpret_cast<const bf16x8*>(&wcatTA[((2 + p) * 8 + cc) * 512 + L * 8]),
               xfhB[cc], gF, 0, 0, 0);
        gG = __builtin_amdgcn_mfma_f32_32x32x16_bf16(
               *reinterpret_cast<const bf16x8*>(&wcatTA[((4 + p) * 8 + cc) * 512 + L * 8]),
               xfhB[cc], gG, 0, 0, 0);
      }
      float tc[16];
      #pragma unroll
      for (int ri = 0; ri < 16; ++ri) {
        float ccv = sigm(gF[ri]) * cx[p * 16 + ri] + sigm(gI[ri]) * tanh_fast(gG[ri]);
        cx[p * 16 + ri] = ccv;
        tc[ri] = tanh_fast(ccv);
      }
      f32x16 gO;
      #pragma unroll
      for (int g = 0; g < 4; ++g) {
        float4 bO = *reinterpret_cast<const float4*>(&sBih[192 + 32 * p + 8 * g + 4 * hf]);
        gO[4*g+0]=bO.x; gO[4*g+1]=bO.y; gO[4*g+2]=bO.z; gO[4*g+3]=bO.w;
      }
      #pragma unroll
      for (int cc = 0; cc < 8; ++cc)
        gO = __builtin_amdgcn_mfma_f32_32x32x16_bf16(
               *reinterpret_cast<const bf16x8*>(&wcatTA[((6 + p) * 8 + cc) * 512 + L * 8]),
               xfhB[cc], gO, 0, 0, 0);
      float hq[16];
      #pragma unroll
      for (int ri = 0; ri < 16; ++ri) hq[ri] = sigm(gO[ri]) * tc[ri];
      hN[2*p]   = cpack8(hq[0], hq[1], hq[2], hq[3], hq[4], hq[5], hq[6], hq[7]);
      hN[2*p+1] = cpack8(hq[8], hq[9], hq[10], hq[11], hq[12], hq[13], hq[14], hq[15]);
    }
    #pragma unroll
    for (int t = 0; t < 4; ++t) xfhB[4 + t] = hN[t];
    // ---- decoder: d1^T, d2^T, pred update, next-xB build (all in regs) ----
    if (de) {
      if (step == TSTEPS) {
        const float* px = xh + ((b * TSTEPS + (TSTEPS - 1)) * 32 + n5) * 11;
        if (hf == 0) { predr[0] = px[0]; predr[1] = px[1]; predr[2] = px[2]; predr[3] = px[3]; }
        else         { predr[0] = px[4]; predr[1] = px[5]; }
        st0 = px[6 + 2 * hf]; st1 = px[7 + 2 * hf]; st2 = px[10];
      }
      f32x16 cD;
      #pragma unroll
      for (int g = 0; g < 4; ++g) {
        float4 bb = *reinterpret_cast<const float4*>(&sBd1[8 * g + 4 * hf]);
        cD[4*g+0] = bb.x; cD[4*g+1] = bb.y; cD[4*g+2] = bb.z; cD[4*g+3] = bb.w;
      }
      #pragma unroll
      for (int cc = 0; cc < 4; ++cc)
        cD = __builtin_amdgcn_mfma_f32_32x32x16_bf16(
               *reinterpret_cast<const bf16x8*>(&wd1TA[cc * 512 + L * 8]), xfhB[4 + cc], cD, 0, 0, 0);
      bf16x8 rB0 = cpack8(fmaxf(cD[0], 0.f), fmaxf(cD[1], 0.f), fmaxf(cD[2], 0.f), fmaxf(cD[3], 0.f),
                          fmaxf(cD[4], 0.f), fmaxf(cD[5], 0.f), fmaxf(cD[6], 0.f), fmaxf(cD[7], 0.f));
      bf16x8 rB1 = cpack8(fmaxf(cD[8], 0.f), fmaxf(cD[9], 0.f), fmaxf(cD[10], 0.f), fmaxf(cD[11], 0.f),
                          fmaxf(cD[12], 0.f), fmaxf(cD[13], 0.f), fmaxf(cD[14], 0.f), fmaxf(cD[15], 0.f));
      f32x16 c2;
      #pragma unroll
      for (int i = 0; i < 4; ++i) c2[i] = sBd2[4 * hf + i];
      #pragma unroll
      for (int i = 4; i < 16; ++i) c2[i] = 0.0f;
      c2 = __builtin_amdgcn_mfma_f32_32x32x16_bf16(
             *reinterpret_cast<const bf16x8*>(&wd2TA[L * 8]), rB0, c2, 0, 0, 0);
      c2 = __builtin_amdgcn_mfma_f32_32x32x16_bf16(
             *reinterpret_cast<const bf16x8*>(&wd2TA[512 + L * 8]), rB1, c2, 0, 0, 0);
      float* op = out + ((b * FUT + (step - TSTEPS)) * 32 + n5) * 6;
      if (hf == 0) {
        float p0 = predr[0] + c2[0];
        float p1 = predr[1] + c2[1];
        float p2 = predr[2] + c2[2];
        float p3 = predr[3] + c2[3];
        predr[0] = p0; predr[1] = p1; predr[2] = p2; predr[3] = p3;
        *reinterpret_cast<float2*>(op + 0) = make_float2(p0, p1);
        *reinterpret_cast<float2*>(op + 2) = make_float2(p2, p3);
      } else {
        float p4 = predr[0] + c2[0];
        float p5 = predr[1] + c2[1];
        predr[0] = p4; predr[1] = p5;
        *reinterpret_cast<float2*>(op + 4) = make_float2(p4, p5);
      }
      // next xB = [pred(6) | stat(5) | 0...] in frag layout, built in regs.
      uint32_t pa = pk2(predr[0], predr[1]);          // hf0:{p0,p1}  hf1:{p4,p5}
      auto sw = __builtin_amdgcn_permlane32_swap(pa, pa, false, false);
      uint32_t d0 = hf ? pk2(st0, st1)  : pa;
      uint32_t d1 = hf ? pk2(st2, 0.0f) : pk2(predr[2], predr[3]);
      uint32_t d2 = hf ? 0u : (uint32_t)sw[1];        // {p4,p5} pulled from hf1
      uint32_t d3 = hf ? 0u : pk2(st0, st1);
      union { uint32x4v u; bf16x8 h; } xo;
      xo.u = uint32x4v{d0, d1, d2, d3};
      xBcur = xo.h;
    }
  }
}

extern "C" void kernel_launch(void* const* d_in, const int* in_sizes, int n_in,
                              void* d_out, int out_size, void* d_ws, size_t ws_size,
                              hipStream_t stream) {
  (void)in_sizes; (void)n_in; (void)d_ws; (void)ws_size; (void)out_size;
  const float* xh   = (const float*)d_in[0];
  const float* adj  = (const float*)d_in[1];
  const float* Wenc = (const float*)d_in[2];
  const float* benc = (const float*)d_in[3];
  const float* Wg1  = (const float*)d_in[4];
  const float* bg1  = (const float*)d_in[5];
  const float* Wg2  = (const float*)d_in[6];
  const float* bg2  = (const float*)d_in[7];
  const float* Wih  = (const float*)d_in[8];
  const float* Whh  = (const float*)d_in[9];
  const float* bih  = (const float*)d_in[10];
  const float* bhh  = (const float*)d_in[11];
  const float* Wd1  = (const float*)d_in[12];
  const float* bd1  = (const float*)d_in[13];
  const float* Wd2  = (const float*)d_in[14];
  const float* bd2  = (const float*)d_in[15];
  float* out = (float*)d_out;
  stgnn_kernel<<<dim3(256), dim3(NT), 0, stream>>>(
      xh, adj, Wenc, benc, Wg1, bg1, Wg2, bg2,
      Wih, Whh, bih, bhh, Wd1, bd1, Wd2, bd2, out);
}

// Round 4
// 945.632 us; speedup vs baseline: 6.2689x; 1.1011x over previous
//
#include <hip/hip_runtime.h>
#include <cstdint>

// WeatherSTGNN persistent kernel, round 9: trans-count cut + bias folds.
// Round 8 calibration: VALU-cycle cuts convert ~1:1 into duration (r7->r8:
// -46% VALU busy -> -45% dur). Remaining VALU: 320 trans (5 exp + 5 rcp per
// cell elem), ~290 acc-init movs + bias LDS reads, packs, fmax.
// Changes vs round 8:
//  1. Fused-denominator LSTM cell (exact fp32 algebra):
//     ccv = [cx*(1+ei)(eg+1) + (eg-1)(1+ef)] / [(1+ef)(1+ei)(eg+1)] -> 1 rcp
//     h   = (ec-1) / [(1+eo)(ec+1)]                                 -> 1 rcp
//     10 trans/elem -> 7 trans/elem, fewer full-rate ops.
//  2. Encoder bias via constant feature slot: sXb slot 11 = 1.0 (sticky),
//     wencTA row 11 = benc -> bias free through MFMA; enc acc init = 0;
//     sBenc deleted (8 LDS reads + 32 movs/step gone).
//  3. wg1B/wg2B fragments hoisted to persistent regs (+64 VGPR, proven-safe
//     named-hoist pattern from r8) -> 16 ds_read_b128/step off the chain.
// Everything else identical to round 8.

#define NT 512
#define TSTEPS 48
#define FUT 48

typedef __bf16 bf16;
typedef __attribute__((ext_vector_type(2))) __bf16 bf16x2;
typedef __attribute__((ext_vector_type(8))) __bf16 bf16x8;
typedef __attribute__((ext_vector_type(16))) float f32x16;
typedef unsigned int uint32x4v __attribute__((ext_vector_type(4)));

#define L2E  1.442695041f
#define L2E2 2.885390082f

__device__ __forceinline__ uint32_t pk2(float x, float y) {
  union { bf16x2 h; uint32_t u; } t;
  t.h[0] = (bf16)x; t.h[1] = (bf16)y;
  return t.u;
}

// C-regs v0..v7 (quads q,q+1 of a 32x32 C tile) -> one bf16x8 A/B-frag chunk.
// frag lanes<32 <- quad q, lanes>=32 <- quad q+1; elems 0-3 from hf=0 source
// half, 4-7 from hf=1. permlane32_swap(a,b): r[0]={a.lo,b.lo}, r[1]={a.hi,b.hi}.
__device__ __forceinline__ bf16x8 cpack8(float v0, float v1, float v2, float v3,
                                         float v4, float v5, float v6, float v7) {
  uint32_t a0 = pk2(v0, v1), a1 = pk2(v2, v3);
  uint32_t b0 = pk2(v4, v5), b1 = pk2(v6, v7);
  auto r0 = __builtin_amdgcn_permlane32_swap(a0, b0, false, false);
  auto r1 = __builtin_amdgcn_permlane32_swap(a1, b1, false, false);
  union { uint32x4v u; bf16x8 h; } o;
  o.u = uint32x4v{(uint32_t)r0[0], (uint32_t)r1[0], (uint32_t)r0[1], (uint32_t)r1[1]};
  return o.h;
}

__global__ __launch_bounds__(NT, 2)
void stgnn_kernel(const float* __restrict__ xh, const float* __restrict__ adj,
                  const float* __restrict__ Wenc, const float* __restrict__ benc,
                  const float* __restrict__ Wg1, const float* __restrict__ bg1,
                  const float* __restrict__ Wg2, const float* __restrict__ bg2,
                  const float* __restrict__ Wih, const float* __restrict__ Whh,
                  const float* __restrict__ bih, const float* __restrict__ bhh,
                  const float* __restrict__ Wd1, const float* __restrict__ bd1,
                  const float* __restrict__ Wd2, const float* __restrict__ bd2,
                  float* __restrict__ out) {
  __shared__ __align__(16) bf16 wcatTA[32768];  // Wcat^T A-frag (8 mt x 8 c)
  __shared__ __align__(16) bf16 wg1B[4096];     // Wg1 B-frag (2 nt x 4 c)
  __shared__ __align__(16) bf16 wg2B[4096];     // Wg2 B-frag
  __shared__ __align__(16) bf16 wencTA[1024];   // Wenc^T A-frag (2 mt x 1 c), row11=benc
  __shared__ __align__(16) bf16 wd1TA[2048];    // Wd1^T A-frag (1 mt x 4 c)
  __shared__ __align__(16) bf16 wd2TA[1024];    // Wd2^T A-frag (1 mt x 2 c, d padded)
  __shared__ __align__(16) bf16 ahHiB[1024];    // Ahat^T hi B-frag (2 c)
  __shared__ __align__(16) bf16 ahLoB[1024];    // Ahat^T lo B-frag (2 c)
  __shared__ __align__(16) float sBg1[64];
  __shared__ __align__(16) float sBg2[64];
  __shared__ __align__(16) float sBih[256];
  __shared__ __align__(16) float sBd1[32];
  __shared__ __align__(16) float sBd2[8];
  __shared__ float sDeg[32];
  __shared__ __align__(16) float sAh[1024];     // normalized Ahat (setup only)
  __shared__ __align__(16) bf16 sXbA[8 * 512];  // per-wave x staging, [node][f pad16]

  const int tid = threadIdx.x;
  const int L   = tid & 63;
  const int w   = tid >> 6;
  const int n5  = L & 31;
  const int hf  = L >> 5;
  const long long b = (long long)blockIdx.x * 8 + w;

  bf16* sXb = sXbA + (w << 9);

  // ---------------- static staging ----------------
  for (int i = tid; i < 1024; i += NT) {
    int f = i >> 6, h = i & 63;
    float v = (f < 11) ? Wenc[f * 64 + h] : (f == 11 ? benc[h] : 0.0f);
    wencTA[(h >> 5) * 512 + ((h & 31) + 32 * ((f >> 3) & 1)) * 8 + (f & 7)] = (bf16)v;
  }
  for (int i = tid; i < 4096; i += NT) {
    int k = i >> 6, n = i & 63;
    int off = (((n >> 5) * 4 + (k >> 4)) * 64 + (n & 31) + 32 * ((k >> 3) & 1)) * 8 + (k & 7);
    wg1B[off] = (bf16)Wg1[i];
    wg2B[off] = (bf16)Wg2[i];
  }
  for (int i = tid; i < 32768; i += NT) {
    int gc = i >> 7, k = i & 127;
    float v = (k < 64) ? Wih[gc * 64 + k] : Whh[gc * 64 + (k - 64)];
    wcatTA[((gc >> 5) * 8 + (k >> 4)) * 512 + ((gc & 31) + 32 * ((k >> 3) & 1)) * 8 + (k & 7)] = (bf16)v;
  }
  for (int i = tid; i < 2048; i += NT) {
    int k = i >> 5, n = i & 31;
    wd1TA[(k >> 4) * 512 + (n + 32 * ((k >> 3) & 1)) * 8 + (k & 7)] = (bf16)Wd1[k * 32 + n];
  }
  for (int i = tid; i < 1024; i += NT) {
    int k = i >> 5, d = i & 31;
    float v = (d < 6) ? Wd2[k * 6 + d] : 0.0f;
    wd2TA[(k >> 4) * 512 + (d + 32 * ((k >> 3) & 1)) * 8 + (k & 7)] = (bf16)v;
  }
  for (int i = tid; i < 64; i += NT) { sBg1[i] = bg1[i]; sBg2[i] = bg2[i]; }
  for (int i = tid; i < 256; i += NT) sBih[i] = bih[i] + bhh[i];
  for (int i = tid; i < 32; i += NT) sBd1[i] = bd1[i];
  if (tid < 8) sBd2[tid] = (tid < 6) ? bd2[tid] : 0.0f;
  if (tid < 32) {
    float s = 0.0f;
    for (int j = 0; j < 32; ++j) s += (j == tid) ? 1.0f : adj[tid * 32 + j];
    sDeg[tid] = 1.0f / sqrtf(fmaxf(s, 1.0f));
  }
  __syncthreads();
  for (int i = tid; i < 1024; i += NT) {
    int ii = i >> 5, jj = i & 31;
    float v = (ii == jj) ? 1.0f : adj[i];
    sAh[i] = sDeg[ii] * v * sDeg[jj];
  }
  __syncthreads();
  // Ahat hi/lo B-fragments into LDS (wave 0 covers all 64 lanes x 2 chunks)
  if (w == 0) {
    #pragma unroll
    for (int c = 0; c < 2; ++c)
      #pragma unroll
      for (int j = 0; j < 8; ++j) {
        int k = 16 * c + 8 * hf + j;
        float v = sAh[n5 * 32 + k];
        bf16 hi = (bf16)v;
        ahHiB[c * 512 + L * 8 + j] = hi;
        ahLoB[c * 512 + L * 8 + j] = (bf16)(v - (float)hi);
      }
  }
  __syncthreads();  // last barrier: everything per-wave / read-only after this

  // controlled hoists: named pre-loop loads survive the per-step clobber.
  // Ahat hi/lo (16) + Wenc (8) + wg1/wg2 chunks (64) ~= 88 persistent VGPRs.
  const bf16x8 aH0 = *reinterpret_cast<const bf16x8*>(&ahHiB[L * 8]);
  const bf16x8 aL0 = *reinterpret_cast<const bf16x8*>(&ahLoB[L * 8]);
  const bf16x8 aH1 = *reinterpret_cast<const bf16x8*>(&ahHiB[512 + L * 8]);
  const bf16x8 aL1 = *reinterpret_cast<const bf16x8*>(&ahLoB[512 + L * 8]);
  const bf16x8 wencR0 = *reinterpret_cast<const bf16x8*>(&wencTA[L * 8]);
  const bf16x8 wencR1 = *reinterpret_cast<const bf16x8*>(&wencTA[512 + L * 8]);
  bf16x8 wg1R[8], wg2R[8];
  #pragma unroll
  for (int c = 0; c < 8; ++c) {
    wg1R[c] = *reinterpret_cast<const bf16x8*>(&wg1B[c * 512 + L * 8]);
    wg2R[c] = *reinterpret_cast<const bf16x8*>(&wg2B[c * 512 + L * 8]);
  }

  // persistent per-wave registers
  float cx[32];
  #pragma unroll
  for (int i = 0; i < 32; ++i) cx[i] = 0.0f;
  bf16x8 xfhB[8];
  #pragma unroll
  for (int t = 0; t < 8; ++t)
    #pragma unroll
    for (int j = 0; j < 8; ++j) xfhB[t][j] = (bf16)0.0f;
  float predr[4] = {0.f, 0.f, 0.f, 0.f};
  float st0 = 0.f, st1 = 0.f, st2 = 0.f;

  // init [node][f pad16]: slot 11 = 1.0 (bias lane, sticky), rest 0
  for (int i = L; i < 512; i += 64) sXb[i] = ((i & 15) == 11) ? (bf16)1.0f : (bf16)0.0f;
  float xpre[6];
  #pragma unroll
  for (int t = 0; t < 6; ++t) {
    int i = L + (t << 6);
    xpre[t] = (i < 352) ? xh[b * (TSTEPS * 352) + i] : 0.0f;
  }
  #pragma unroll
  for (int t = 0; t < 6; ++t) {
    int i = L + (t << 6);
    if (i < 352) { int j = i / 11, f = i - j * 11; sXb[(j << 4) + f] = (bf16)xpre[t]; }
  }
  #pragma unroll
  for (int t = 0; t < 6; ++t) {
    int i = L + (t << 6);
    if (i < 352) xpre[t] = xh[b * (TSTEPS * 352) + 352 + i];
  }
  bf16x8 xBcur = *reinterpret_cast<const bf16x8*>(&sXb[(n5 << 4) + (hf << 3)]);

  #pragma unroll 1
  for (int step = 0; step < TSTEPS + FUT; ++step) {
    // Anti-LICM fence (round-6 lesson: blanket hoist -> scratch spill).
    asm volatile("" ::: "memory");
    const bool de = (step >= TSTEPS);
    const bf16x8 xB = xBcur;  // staged/built one step ago -> no latency here
    if (!de) {
      if (step + 1 < TSTEPS) {
        #pragma unroll
        for (int t = 0; t < 6; ++t) {
          int i = L + (t << 6);
          if (i < 352) { int j = i / 11, f = i - j * 11; sXb[(j << 4) + f] = (bf16)xpre[t]; }
        }
      }
      if (step + 2 < TSTEPS) {
        #pragma unroll
        for (int t = 0; t < 6; ++t) {
          int i = L + (t << 6);
          if (i < 352) xpre[t] = xh[b * (TSTEPS * 352) + (step + 2) * 352 + i];
        }
      }
      xBcur = *reinterpret_cast<const bf16x8*>(&sXb[(n5 << 4) + (hf << 3)]);
    }
    // ---- enc^T = relu(Wenc^T @ x^T), bias via x slot 11 = 1.0 ----
    bf16x8 rA[4];
    #pragma unroll
    for (int mt = 0; mt < 2; ++mt) {
      f32x16 c;
      #pragma unroll
      for (int i = 0; i < 16; ++i) c[i] = 0.0f;
      c = __builtin_amdgcn_mfma_f32_32x32x16_bf16(mt ? wencR1 : wencR0, xB, c, 0, 0, 0);
      rA[2*mt]   = cpack8(fmaxf(c[0], 0.f), fmaxf(c[1], 0.f), fmaxf(c[2], 0.f), fmaxf(c[3], 0.f),
                          fmaxf(c[4], 0.f), fmaxf(c[5], 0.f), fmaxf(c[6], 0.f), fmaxf(c[7], 0.f));
      rA[2*mt+1] = cpack8(fmaxf(c[8], 0.f), fmaxf(c[9], 0.f), fmaxf(c[10], 0.f), fmaxf(c[11], 0.f),
                          fmaxf(c[12], 0.f), fmaxf(c[13], 0.f), fmaxf(c[14], 0.f), fmaxf(c[15], 0.f));
    }
    // ---- t1 = enc @ Wg1 (weights in regs) ----
    bf16x8 nA[4];
    #pragma unroll
    for (int nt = 0; nt < 2; ++nt) {
      f32x16 c;
      #pragma unroll
      for (int i = 0; i < 16; ++i) c[i] = 0.0f;
      #pragma unroll
      for (int cc = 0; cc < 4; ++cc)
        c = __builtin_amdgcn_mfma_f32_32x32x16_bf16(rA[cc], wg1R[nt * 4 + cc], c, 0, 0, 0);
      nA[2*nt]   = cpack8(c[0], c[1], c[2], c[3], c[4], c[5], c[6], c[7]);
      nA[2*nt+1] = cpack8(c[8], c[9], c[10], c[11], c[12], c[13], c[14], c[15]);
    }
    // ---- s1^T = relu(t1^T @ Ahat^T + bg1) ----
    #pragma unroll
    for (int mt = 0; mt < 2; ++mt) {
      f32x16 c;
      #pragma unroll
      for (int g = 0; g < 4; ++g) {
        float4 bb = *reinterpret_cast<const float4*>(&sBg1[32 * mt + 8 * g + 4 * hf]);
        c[4*g+0] = bb.x; c[4*g+1] = bb.y; c[4*g+2] = bb.z; c[4*g+3] = bb.w;
      }
      c = __builtin_amdgcn_mfma_f32_32x32x16_bf16(nA[mt * 2 + 0], aH0, c, 0, 0, 0);
      c = __builtin_amdgcn_mfma_f32_32x32x16_bf16(nA[mt * 2 + 0], aL0, c, 0, 0, 0);
      c = __builtin_amdgcn_mfma_f32_32x32x16_bf16(nA[mt * 2 + 1], aH1, c, 0, 0, 0);
      c = __builtin_amdgcn_mfma_f32_32x32x16_bf16(nA[mt * 2 + 1], aL1, c, 0, 0, 0);
      rA[2*mt]   = cpack8(fmaxf(c[0], 0.f), fmaxf(c[1], 0.f), fmaxf(c[2], 0.f), fmaxf(c[3], 0.f),
                          fmaxf(c[4], 0.f), fmaxf(c[5], 0.f), fmaxf(c[6], 0.f), fmaxf(c[7], 0.f));
      rA[2*mt+1] = cpack8(fmaxf(c[8], 0.f), fmaxf(c[9], 0.f), fmaxf(c[10], 0.f), fmaxf(c[11], 0.f),
                          fmaxf(c[12], 0.f), fmaxf(c[13], 0.f), fmaxf(c[14], 0.f), fmaxf(c[15], 0.f));
    }
    // ---- t2 = s1 @ Wg2 (weights in regs) ----
    #pragma unroll
    for (int nt = 0; nt < 2; ++nt) {
      f32x16 c;
      #pragma unroll
      for (int i = 0; i < 16; ++i) c[i] = 0.0f;
      #pragma unroll
      for (int cc = 0; cc < 4; ++cc)
        c = __builtin_amdgcn_mfma_f32_32x32x16_bf16(rA[cc], wg2R[nt * 4 + cc], c, 0, 0, 0);
      nA[2*nt]   = cpack8(c[0], c[1], c[2], c[3], c[4], c[5], c[6], c[7]);
      nA[2*nt+1] = cpack8(c[8], c[9], c[10], c[11], c[12], c[13], c[14], c[15]);
    }
    // ---- xf^T = relu(t2^T @ Ahat^T + bg2) -> xfhB[0..3] ----
    #pragma unroll
    for (int mt = 0; mt < 2; ++mt) {
      f32x16 c;
      #pragma unroll
      for (int g = 0; g < 4; ++g) {
        float4 bb = *reinterpret_cast<const float4*>(&sBg2[32 * mt + 8 * g + 4 * hf]);
        c[4*g+0] = bb.x; c[4*g+1] = bb.y; c[4*g+2] = bb.z; c[4*g+3] = bb.w;
      }
      c = __builtin_amdgcn_mfma_f32_32x32x16_bf16(nA[mt * 2 + 0], aH0, c, 0, 0, 0);
      c = __builtin_amdgcn_mfma_f32_32x32x16_bf16(nA[mt * 2 + 0], aL0, c, 0, 0, 0);
      c = __builtin_amdgcn_mfma_f32_32x32x16_bf16(nA[mt * 2 + 1], aH1, c, 0, 0, 0);
      c = __builtin_amdgcn_mfma_f32_32x32x16_bf16(nA[mt * 2 + 1], aL1, c, 0, 0, 0);
      xfhB[2*mt]   = cpack8(fmaxf(c[0], 0.f), fmaxf(c[1], 0.f), fmaxf(c[2], 0.f), fmaxf(c[3], 0.f),
                            fmaxf(c[4], 0.f), fmaxf(c[5], 0.f), fmaxf(c[6], 0.f), fmaxf(c[7], 0.f));
      xfhB[2*mt+1] = cpack8(fmaxf(c[8], 0.f), fmaxf(c[9], 0.f), fmaxf(c[10], 0.f), fmaxf(c[11], 0.f),
                            fmaxf(c[12], 0.f), fmaxf(c[13], 0.f), fmaxf(c[14], 0.f), fmaxf(c[15], 0.f));
    }
    // ---- LSTM, split gates, fused-denominator cell math ----
    bf16x8 hN[4];
    #pragma unroll
    for (int p = 0; p < 2; ++p) {
      f32x16 gI, gF, gG;
      #pragma unroll
      for (int g = 0; g < 4; ++g) {
        float4 bI = *reinterpret_cast<const float4*>(&sBih[      32 * p + 8 * g + 4 * hf]);
        float4 bF = *reinterpret_cast<const float4*>(&sBih[ 64 + 32 * p + 8 * g + 4 * hf]);
        float4 bG = *reinterpret_cast<const float4*>(&sBih[128 + 32 * p + 8 * g + 4 * hf]);
        gI[4*g+0]=bI.x; gI[4*g+1]=bI.y; gI[4*g+2]=bI.z; gI[4*g+3]=bI.w;
        gF[4*g+0]=bF.x; gF[4*g+1]=bF.y; gF[4*g+2]=bF.z; gF[4*g+3]=bF.w;
        gG[4*g+0]=bG.x; gG[4*g+1]=bG.y; gG[4*g+2]=bG.z; gG[4*g+3]=bG.w;
      }
      #pragma unroll
      for (int cc = 0; cc < 8; ++cc) {
        gI = __builtin_amdgcn_mfma_f32_32x32x16_bf16(
               *reinterpret_cast<const bf16x8*>(&wcatTA[((0 + p) * 8 + cc) * 512 + L * 8]),
               xfhB[cc], gI, 0, 0, 0);
        gF = __builtin_amdgcn_mfma_f32_32x32x16_bf16(
               *reinterpret_cast<const bf16x8*>(&wcatTA[((2 + p) * 8 + cc) * 512 + L * 8]),
               xfhB[cc], gF, 0, 0, 0);
        gG = __builtin_amdgcn_mfma_f32_32x32x16_bf16(
               *reinterpret_cast<const bf16x8*>(&wcatTA[((4 + p) * 8 + cc) * 512 + L * 8]),
               xfhB[cc], gG, 0, 0, 0);
      }
      // ccv = cx/(1+ef) + (eg-1)/((1+ei)(eg+1)): single rcp, exact algebra
      #pragma unroll
      for (int ri = 0; ri < 16; ++ri) {
        float ef = __builtin_amdgcn_exp2f(gF[ri] * -L2E);
        float ei = __builtin_amdgcn_exp2f(gI[ri] * -L2E);
        float eg = __builtin_amdgcn_exp2f(gG[ri] * L2E2);
        float D1 = 1.0f + ef;
        float A  = 1.0f + ei;
        float T  = __builtin_fmaf(A, eg, A);               // (1+ei)(eg+1)
        float t1 = __builtin_fmaf(eg, D1, -D1);            // (eg-1)(1+ef)
        float num = __builtin_fmaf(cx[p * 16 + ri], T, t1);
        cx[p * 16 + ri] = num * __builtin_amdgcn_rcpf(D1 * T);
      }
      f32x16 gO;
      #pragma unroll
      for (int g = 0; g < 4; ++g) {
        float4 bO = *reinterpret_cast<const float4*>(&sBih[192 + 32 * p + 8 * g + 4 * hf]);
        gO[4*g+0]=bO.x; gO[4*g+1]=bO.y; gO[4*g+2]=bO.z; gO[4*g+3]=bO.w;
      }
      #pragma unroll
      for (int cc = 0; cc < 8; ++cc)
        gO = __builtin_amdgcn_mfma_f32_32x32x16_bf16(
               *reinterpret_cast<const bf16x8*>(&wcatTA[((6 + p) * 8 + cc) * 512 + L * 8]),
               xfhB[cc], gO, 0, 0, 0);
      // h = (ec-1)/((1+eo)(ec+1)): single rcp
      float hq[16];
      #pragma unroll
      for (int ri = 0; ri < 16; ++ri) {
        float eo = __builtin_amdgcn_exp2f(gO[ri] * -L2E);
        float ec = __builtin_amdgcn_exp2f(cx[p * 16 + ri] * L2E2);
        float B1 = 1.0f + eo;
        float T2 = __builtin_fmaf(B1, ec, B1);             // (1+eo)(ec+1)
        hq[ri] = (ec - 1.0f) * __builtin_amdgcn_rcpf(T2);
      }
      hN[2*p]   = cpack8(hq[0], hq[1], hq[2], hq[3], hq[4], hq[5], hq[6], hq[7]);
      hN[2*p+1] = cpack8(hq[8], hq[9], hq[10], hq[11], hq[12], hq[13], hq[14], hq[15]);
    }
    #pragma unroll
    for (int t = 0; t < 4; ++t) xfhB[4 + t] = hN[t];
    // ---- decoder: d1^T, d2^T, pred update, next-xB build (all in regs) ----
    if (de) {
      if (step == TSTEPS) {
        const float* px = xh + ((b * TSTEPS + (TSTEPS - 1)) * 32 + n5) * 11;
        if (hf == 0) { predr[0] = px[0]; predr[1] = px[1]; predr[2] = px[2]; predr[3] = px[3]; }
        else         { predr[0] = px[4]; predr[1] = px[5]; }
        st0 = px[6 + 2 * hf]; st1 = px[7 + 2 * hf]; st2 = px[10];
      }
      f32x16 cD;
      #pragma unroll
      for (int g = 0; g < 4; ++g) {
        float4 bb = *reinterpret_cast<const float4*>(&sBd1[8 * g + 4 * hf]);
        cD[4*g+0] = bb.x; cD[4*g+1] = bb.y; cD[4*g+2] = bb.z; cD[4*g+3] = bb.w;
      }
      #pragma unroll
      for (int cc = 0; cc < 4; ++cc)
        cD = __builtin_amdgcn_mfma_f32_32x32x16_bf16(
               *reinterpret_cast<const bf16x8*>(&wd1TA[cc * 512 + L * 8]), xfhB[4 + cc], cD, 0, 0, 0);
      bf16x8 rB0 = cpack8(fmaxf(cD[0], 0.f), fmaxf(cD[1], 0.f), fmaxf(cD[2], 0.f), fmaxf(cD[3], 0.f),
                          fmaxf(cD[4], 0.f), fmaxf(cD[5], 0.f), fmaxf(cD[6], 0.f), fmaxf(cD[7], 0.f));
      bf16x8 rB1 = cpack8(fmaxf(cD[8], 0.f), fmaxf(cD[9], 0.f), fmaxf(cD[10], 0.f), fmaxf(cD[11], 0.f),
                          fmaxf(cD[12], 0.f), fmaxf(cD[13], 0.f), fmaxf(cD[14], 0.f), fmaxf(cD[15], 0.f));
      f32x16 c2;
      #pragma unroll
      for (int i = 0; i < 4; ++i) c2[i] = sBd2[4 * hf + i];
      #pragma unroll
      for (int i = 4; i < 16; ++i) c2[i] = 0.0f;
      c2 = __builtin_amdgcn_mfma_f32_32x32x16_bf16(
             *reinterpret_cast<const bf16x8*>(&wd2TA[L * 8]), rB0, c2, 0, 0, 0);
      c2 = __builtin_amdgcn_mfma_f32_32x32x16_bf16(
             *reinterpret_cast<const bf16x8*>(&wd2TA[512 + L * 8]), rB1, c2, 0, 0, 0);
      float* op = out + ((b * FUT + (step - TSTEPS)) * 32 + n5) * 6;
      if (hf == 0) {
        float p0 = predr[0] + c2[0];
        float p1 = predr[1] + c2[1];
        float p2 = predr[2] + c2[2];
        float p3 = predr[3] + c2[3];
        predr[0] = p0; predr[1] = p1; predr[2] = p2; predr[3] = p3;
        *reinterpret_cast<float2*>(op + 0) = make_float2(p0, p1);
        *reinterpret_cast<float2*>(op + 2) = make_float2(p2, p3);
      } else {
        float p4 = predr[0] + c2[0];
        float p5 = predr[1] + c2[1];
        predr[0] = p4; predr[1] = p5;
        *reinterpret_cast<float2*>(op + 4) = make_float2(p4, p5);
      }
      // next xB = [pred(6) | stat(5) | 1.0 bias | 0...] in frag layout.
      uint32_t pa = pk2(predr[0], predr[1]);          // hf0:{p0,p1}  hf1:{p4,p5}
      auto sw = __builtin_amdgcn_permlane32_swap(pa, pa, false, false);
      uint32_t d0 = hf ? pk2(st0, st1)  : pa;
      uint32_t d1 = hf ? pk2(st2, 1.0f) : pk2(predr[2], predr[3]);  // feat11=1.0
      uint32_t d2 = hf ? 0u : (uint32_t)sw[1];        // {p4,p5} pulled from hf1
      uint32_t d3 = hf ? 0u : pk2(st0, st1);
      union { uint32x4v u; bf16x8 h; } xo;
      xo.u = uint32x4v{d0, d1, d2, d3};
      xBcur = xo.h;
    }
  }
}

extern "C" void kernel_launch(void* const* d_in, const int* in_sizes, int n_in,
                              void* d_out, int out_size, void* d_ws, size_t ws_size,
                              hipStream_t stream) {
  (void)in_sizes; (void)n_in; (void)d_ws; (void)ws_size; (void)out_size;
  const float* xh   = (const float*)d_in[0];
  const float* adj  = (const float*)d_in[1];
  const float* Wenc = (const float*)d_in[2];
  const float* benc = (const float*)d_in[3];
  const float* Wg1  = (const float*)d_in[4];
  const float* bg1  = (const float*)d_in[5];
  const float* Wg2  = (const float*)d_in[6];
  const float* bg2  = (const float*)d_in[7];
  const float* Wih  = (const float*)d_in[8];
  const float* Whh  = (const float*)d_in[9];
  const float* bih  = (const float*)d_in[10];
  const float* bhh  = (const float*)d_in[11];
  const float* Wd1  = (const float*)d_in[12];
  const float* bd1  = (const float*)d_in[13];
  const float* Wd2  = (const float*)d_in[14];
  const float* bd2  = (const float*)d_in[15];
  float* out = (float*)d_out;
  stgnn_kernel<<<dim3(256), dim3(NT), 0, stream>>>(
      xh, adj, Wenc, benc, Wg1, bg1, Wg2, bg2,
      Wih, Whh, bih, bhh, Wd1, bd1, Wd2, bd2, out);
}